// Round 1
// baseline (3997.317 us; speedup 1.0000x reference)
//
#include <hip/hip_runtime.h>
#include <math.h>

// Problem constants (fixed shapes)
#define BB   4
#define LL   1024
#define MM   128
#define RR   512
#define HID  1024
#define NH   16
#define NE   42
#define EMB  768
#define NBK  12          // EMB/64
#define NC   97
#define PJ   128
#define NROWS 2048       // BB*RR

// ---------------------------------------------------------------------------
// K1: per-doc entity member lists + counts
// ---------------------------------------------------------------------------
__global__ __launch_bounds__(128) void k_members(const int* __restrict__ labels,
                                                 int* __restrict__ counts,
                                                 int* __restrict__ members) {
    int b = blockIdx.x;
    __shared__ int cnt[NE];
    int tid = threadIdx.x;
    if (tid < NE) cnt[tid] = 0;
    __syncthreads();
    if (tid < MM) {
        int lab = labels[b * MM + tid];
        int pos = atomicAdd(&cnt[lab], 1);
        members[(b * NE + lab) * MM + pos] = tid;
    }
    __syncthreads();
    if (tid < NE) counts[b * NE + tid] = cnt[tid];
}

// ---------------------------------------------------------------------------
// K2: ent_emb[b,e,d] = logsumexp over members of ent_lhs[b,m,d] (0 if empty)
// ---------------------------------------------------------------------------
__global__ __launch_bounds__(256) void k_entemb(const float* __restrict__ ent,
                                                const int* __restrict__ counts,
                                                const int* __restrict__ members,
                                                float* __restrict__ ent_emb) {
    int be = blockIdx.x;              // b*NE + e
    int b  = be / NE;
    int c  = counts[be];
    int tid = threadIdx.x;
    if (c == 0) {
#pragma unroll
        for (int u = 0; u < 4; ++u)
            ent_emb[(size_t)be * HID + tid + u * 256] = 0.0f;
        return;
    }
    const int* mem = members + be * MM;
    const float* base = ent + (size_t)b * MM * HID;
#pragma unroll
    for (int u = 0; u < 4; ++u) {
        int d = tid + u * 256;
        float mx = -3.0e38f;
        for (int k = 0; k < c; ++k) {
            float x = base[(size_t)mem[k] * HID + d];
            mx = fmaxf(mx, x);
        }
        float s = 0.0f;
        for (int k = 0; k < c; ++k) {
            float x = base[(size_t)mem[k] * HID + d];
            s += expf(x - mx);
        }
        ent_emb[(size_t)be * HID + d] = logf(s) + mx;
    }
}

// ---------------------------------------------------------------------------
// K3: attn_mean[b,e,h,l] = mean over members of attn[b,h,m,l]
// ---------------------------------------------------------------------------
__global__ __launch_bounds__(256) void k_attnmean(const float* __restrict__ attn,
                                                  const int* __restrict__ counts,
                                                  const int* __restrict__ members,
                                                  float* __restrict__ am) {
    int be = blockIdx.x;              // b*NE + e
    int hh = blockIdx.y;
    int b  = be / NE;
    int c  = counts[be];
    const int* mem = members + be * MM;
    float inv = 1.0f / (float)((c > 0) ? c : 1);
    const float* abase = attn + ((size_t)(b * NH + hh)) * MM * LL;
    int tid = threadIdx.x;
#pragma unroll
    for (int u = 0; u < 4; ++u) {
        int l = tid + u * 256;
        float s = 0.0f;
        for (int k = 0; k < c; ++k) s += abase[(size_t)mem[k] * LL + l];
        am[((size_t)be * NH + hh) * LL + l] = s * inv;
    }
}

// ---------------------------------------------------------------------------
// K4: hta[b,r,l] = normalized mean_h attn_mean[b,e0,h,l]*attn_mean[b,e1,h,l]
// ---------------------------------------------------------------------------
__global__ __launch_bounds__(256) void k_hta(const float* __restrict__ am,
                                             const int* __restrict__ hts,
                                             float* __restrict__ hta) {
    int br = blockIdx.x;              // b*RR + r
    int b  = br >> 9;
    int e0 = hts[br * 2 + 0];
    int e1 = hts[br * 2 + 1];
    const float* a0 = am + ((size_t)(b * NE + e0)) * NH * LL;
    const float* a1 = am + ((size_t)(b * NE + e1)) * NH * LL;
    int tid = threadIdx.x;
    float v[4] = {0.f, 0.f, 0.f, 0.f};
    for (int hh = 0; hh < NH; ++hh) {
        const float* p0 = a0 + hh * LL;
        const float* p1 = a1 + hh * LL;
#pragma unroll
        for (int u = 0; u < 4; ++u) {
            int l = tid + u * 256;
            v[u] = fmaf(p0[l], p1[l], v[u]);
        }
    }
    float part = 0.f;
#pragma unroll
    for (int u = 0; u < 4; ++u) { v[u] *= (1.0f / 16.0f); part += v[u]; }
    __shared__ float red[256];
    red[tid] = part;
    __syncthreads();
    for (int s = 128; s > 0; s >>= 1) {
        if (tid < s) red[tid] += red[tid + s];
        __syncthreads();
    }
    float scale = 1.0f / (red[0] + 1e-5f);
#pragma unroll
    for (int u = 0; u < 4; ++u)
        hta[(size_t)br * LL + tid + u * 256] = v[u] * scale;
}

// ---------------------------------------------------------------------------
// K5: rel[b] = hta[b] (512x1024) @ seq[b] (1024x1024)   tiled fp32 GEMM
// ---------------------------------------------------------------------------
__global__ __launch_bounds__(256) void k_rel(const float* __restrict__ hta,
                                             const float* __restrict__ seq,
                                             float* __restrict__ rel) {
    int b = blockIdx.z;
    const float* A  = hta + (size_t)b * RR * LL;
    const float* Bm = seq + (size_t)b * LL * HID;
    float* C = rel + (size_t)b * RR * HID;
    __shared__ float As[16][68];
    __shared__ float Bs[16][68];
    int tid = threadIdx.x;
    int tx = tid & 15, ty = tid >> 4;
    int row0 = blockIdx.x * 64, col0 = blockIdx.y * 64;
    float acc[4][4] = {};
    for (int k0 = 0; k0 < LL; k0 += 16) {
        {   // A tile 64x16 (float4 along k)
            int kk4 = (tid & 3) << 2, m = tid >> 2;
            float4 va = *(const float4*)&A[(size_t)(row0 + m) * LL + k0 + kk4];
            As[kk4 + 0][m] = va.x; As[kk4 + 1][m] = va.y;
            As[kk4 + 2][m] = va.z; As[kk4 + 3][m] = va.w;
        }
        {   // B tile 16x64 (float4 along n)
            int n4 = (tid & 15) << 2, kk = tid >> 4;
            float4 vb = *(const float4*)&Bm[(size_t)(k0 + kk) * HID + col0 + n4];
            *(float4*)&Bs[kk][n4] = vb;
        }
        __syncthreads();
#pragma unroll
        for (int kk = 0; kk < 16; ++kk) {
            float4 a4 = *(const float4*)&As[kk][ty << 2];
            float4 b4 = *(const float4*)&Bs[kk][tx << 2];
            float av[4] = {a4.x, a4.y, a4.z, a4.w};
            float bv[4] = {b4.x, b4.y, b4.z, b4.w};
#pragma unroll
            for (int q = 0; q < 4; ++q)
#pragma unroll
                for (int p = 0; p < 4; ++p)
                    acc[q][p] = fmaf(av[q], bv[p], acc[q][p]);
        }
        __syncthreads();
    }
#pragma unroll
    for (int q = 0; q < 4; ++q)
#pragma unroll
        for (int p = 0; p < 4; ++p)
            C[(size_t)(row0 + (ty << 2) + q) * HID + col0 + (tx << 2) + p] = acc[q][p];
}

// ---------------------------------------------------------------------------
// K6: h/t = tanh( [gather(ent_emb) | rel] (2048x2048) @ W (2048x768) + bias )
// ---------------------------------------------------------------------------
__global__ __launch_bounds__(256) void k_headtail(const float* __restrict__ ent_emb,
                                                  const float* __restrict__ rel,
                                                  const int* __restrict__ hts,
                                                  const float* __restrict__ W,
                                                  const float* __restrict__ bias,
                                                  float* __restrict__ out,
                                                  int htcol) {
    __shared__ float As[16][68];
    __shared__ float Bs[16][68];
    __shared__ int eofs[64];
    __shared__ int rofs[64];
    int tid = threadIdx.x;
    int tx = tid & 15, ty = tid >> 4;
    int row0 = blockIdx.x * 64, col0 = blockIdx.y * 64;
    if (tid < 64) {
        int r = row0 + tid;
        int b = r >> 9, rr = r & 511;
        int e = hts[(b * RR + rr) * 2 + htcol];
        eofs[tid] = (b * NE + e) * HID;
        rofs[tid] = (b * RR + rr) * HID;
    }
    __syncthreads();
    float acc[4][4] = {};
    for (int k0 = 0; k0 < 2 * HID; k0 += 16) {
        if (k0 < HID) {
#pragma unroll
            for (int u = 0; u < 4; ++u) {
                int idx = tid + u * 256;
                int m = idx >> 4, kk = idx & 15;
                As[kk][m] = ent_emb[(size_t)eofs[m] + k0 + kk];
            }
        } else {
#pragma unroll
            for (int u = 0; u < 4; ++u) {
                int idx = tid + u * 256;
                int m = idx >> 4, kk = idx & 15;
                As[kk][m] = rel[(size_t)rofs[m] + (k0 - HID) + kk];
            }
        }
        {
            int n4 = (tid & 15) << 2, kk = tid >> 4;
            float4 vb = *(const float4*)&W[(size_t)(k0 + kk) * EMB + col0 + n4];
            *(float4*)&Bs[kk][n4] = vb;
        }
        __syncthreads();
#pragma unroll
        for (int kk = 0; kk < 16; ++kk) {
            float4 a4 = *(const float4*)&As[kk][ty << 2];
            float4 b4 = *(const float4*)&Bs[kk][tx << 2];
            float av[4] = {a4.x, a4.y, a4.z, a4.w};
            float bv[4] = {b4.x, b4.y, b4.z, b4.w};
#pragma unroll
            for (int q = 0; q < 4; ++q)
#pragma unroll
                for (int p = 0; p < 4; ++p)
                    acc[q][p] = fmaf(av[q], bv[p], acc[q][p]);
        }
        __syncthreads();
    }
#pragma unroll
    for (int q = 0; q < 4; ++q)
#pragma unroll
        for (int p = 0; p < 4; ++p) {
            int cc = col0 + (tx << 2) + p;
            out[(size_t)(row0 + (ty << 2) + q) * EMB + cc] =
                tanhf(acc[q][p] + bias[cc]);
        }
}

// ---------------------------------------------------------------------------
// K7: embeds = bl @ W_bil + b_bil, bl generated on the fly from h,t
//     bl[r, nb*4096 + i*64 + j] = h[r, nb*64+i] * t[r, nb*64+j]
// ---------------------------------------------------------------------------
__global__ __launch_bounds__(256) void k_bilinear(const float* __restrict__ hm,
                                                  const float* __restrict__ tm,
                                                  const float* __restrict__ Wb,
                                                  const float* __restrict__ bb,
                                                  float* __restrict__ embeds) {
    __shared__ float Hst[64][68];   // [i][row]
    __shared__ float Tst[64][68];   // [j][row]
    __shared__ float Ws[64][68];    // [j][o]
    int tid = threadIdx.x;
    int tx = tid & 15, ty = tid >> 4;
    int row0 = blockIdx.x * 64, col0 = blockIdx.y * 64;
    float acc[4][4] = {};
    for (int nb = 0; nb < NBK; ++nb) {
        __syncthreads();   // previous nb's compute done -> safe to overwrite H/T
#pragma unroll
        for (int u = 0; u < 4; ++u) {
            int idx = tid + u * 256;          // 0..1023
            int kk4 = (idx & 15) << 2, r = idx >> 4;
            float4 vh = *(const float4*)&hm[(size_t)(row0 + r) * EMB + nb * 64 + kk4];
            Hst[kk4 + 0][r] = vh.x; Hst[kk4 + 1][r] = vh.y;
            Hst[kk4 + 2][r] = vh.z; Hst[kk4 + 3][r] = vh.w;
            float4 vt = *(const float4*)&tm[(size_t)(row0 + r) * EMB + nb * 64 + kk4];
            Tst[kk4 + 0][r] = vt.x; Tst[kk4 + 1][r] = vt.y;
            Tst[kk4 + 2][r] = vt.z; Tst[kk4 + 3][r] = vt.w;
        }
        for (int i = 0; i < 64; ++i) {
            __syncthreads();   // prev compute done (Ws free), H/T visible
#pragma unroll
            for (int u = 0; u < 4; ++u) {
                int idx = tid + u * 256;      // 0..1023
                int o4 = (idx & 15) << 2, j = idx >> 4;
                *(float4*)&Ws[j][o4] =
                    *(const float4*)&Wb[(size_t)(nb * 4096 + i * 64 + j) * EMB + col0 + o4];
            }
            __syncthreads();
            float4 hv = *(const float4*)&Hst[i][ty << 2];
#pragma unroll 8
            for (int j = 0; j < 64; ++j) {
                float4 tv = *(const float4*)&Tst[j][ty << 2];
                float4 wv = *(const float4*)&Ws[j][tx << 2];
                float a0 = hv.x * tv.x, a1 = hv.y * tv.y;
                float a2 = hv.z * tv.z, a3 = hv.w * tv.w;
                acc[0][0] = fmaf(a0, wv.x, acc[0][0]);
                acc[0][1] = fmaf(a0, wv.y, acc[0][1]);
                acc[0][2] = fmaf(a0, wv.z, acc[0][2]);
                acc[0][3] = fmaf(a0, wv.w, acc[0][3]);
                acc[1][0] = fmaf(a1, wv.x, acc[1][0]);
                acc[1][1] = fmaf(a1, wv.y, acc[1][1]);
                acc[1][2] = fmaf(a1, wv.z, acc[1][2]);
                acc[1][3] = fmaf(a1, wv.w, acc[1][3]);
                acc[2][0] = fmaf(a2, wv.x, acc[2][0]);
                acc[2][1] = fmaf(a2, wv.y, acc[2][1]);
                acc[2][2] = fmaf(a2, wv.z, acc[2][2]);
                acc[2][3] = fmaf(a2, wv.w, acc[2][3]);
                acc[3][0] = fmaf(a3, wv.x, acc[3][0]);
                acc[3][1] = fmaf(a3, wv.y, acc[3][1]);
                acc[3][2] = fmaf(a3, wv.z, acc[3][2]);
                acc[3][3] = fmaf(a3, wv.w, acc[3][3]);
            }
        }
    }
#pragma unroll
    for (int q = 0; q < 4; ++q)
#pragma unroll
        for (int p = 0; p < 4; ++p) {
            int cc = col0 + (tx << 2) + p;
            embeds[(size_t)(row0 + (ty << 2) + q) * EMB + cc] = acc[q][p] + bb[cc];
        }
}

// ---------------------------------------------------------------------------
// K8: class_logits = embeds @ W_cls + b_cls ; proj = tanh(embeds @ W_proj + b)
// ---------------------------------------------------------------------------
__global__ __launch_bounds__(256) void k_cls(const float* __restrict__ embeds,
                                             const float* __restrict__ Wc,
                                             const float* __restrict__ bc,
                                             const float* __restrict__ Wp,
                                             const float* __restrict__ bp,
                                             float* __restrict__ cls_out,
                                             float* __restrict__ proj_out) {
    __shared__ float Es[16][769];
    int row0 = blockIdx.x * 16;
    int tid = threadIdx.x;
    for (int rr = 0; rr < 16; ++rr)
        for (int k = tid; k < EMB; k += 256)
            Es[rr][k] = embeds[(size_t)(row0 + rr) * EMB + k];
    __syncthreads();
    const int TOT = NC + PJ;   // 225
    for (int oi = tid; oi < 16 * TOT; oi += 256) {
        int r = oi / TOT;
        int c = oi - r * TOT;
        if (c < NC) {
            float acc = bc[c];
            for (int k = 0; k < EMB; ++k)
                acc = fmaf(Es[r][k], Wc[(size_t)k * NC + c], acc);
            cls_out[(size_t)(row0 + r) * NC + c] = acc;
        } else {
            int p = c - NC;
            float acc = bp[p];
            for (int k = 0; k < EMB; ++k)
                acc = fmaf(Es[r][k], Wp[(size_t)k * PJ + p], acc);
            proj_out[(size_t)(row0 + r) * PJ + p] = tanhf(acc);
        }
    }
}

// ---------------------------------------------------------------------------
extern "C" void kernel_launch(void* const* d_in, const int* in_sizes, int n_in,
                              void* d_out, int out_size, void* d_ws, size_t ws_size,
                              hipStream_t stream) {
    const float* seq    = (const float*)d_in[0];
    const float* ent    = (const float*)d_in[1];
    const float* attn   = (const float*)d_in[2];
    const int*   labels = (const int*)d_in[3];
    const int*   hts    = (const int*)d_in[4];
    const float* W_head = (const float*)d_in[5];
    const float* b_head = (const float*)d_in[6];
    const float* W_tail = (const float*)d_in[7];
    const float* b_tail = (const float*)d_in[8];
    const float* W_bil  = (const float*)d_in[9];
    const float* b_bil  = (const float*)d_in[10];
    const float* W_cls  = (const float*)d_in[11];
    const float* b_cls  = (const float*)d_in[12];
    const float* W_proj = (const float*)d_in[13];
    const float* b_proj = (const float*)d_in[14];

    // workspace layout (~41 MB)
    int*   counts   = (int*)d_ws;                 // 168 (reserve 256)
    int*   members  = counts + 256;               // 21504
    float* ent_emb  = (float*)(members + 21504);  // 172032
    float* am       = ent_emb + 172032;           // 2752512
    float* hta      = am + 2752512;               // 2097152
    float* rel      = hta + 2097152;              // 2097152
    float* hbuf     = rel + 2097152;              // 1572864
    float* tbuf     = hbuf + 1572864;             // 1572864

    float* embeds_out = (float*)d_out;                    // 2048*768
    float* cls_out    = embeds_out + NROWS * EMB;         // 2048*97
    float* proj_out   = cls_out + NROWS * NC;             // 2048*128

    hipLaunchKernelGGL(k_members, dim3(BB), dim3(128), 0, stream,
                       labels, counts, members);
    hipLaunchKernelGGL(k_entemb, dim3(BB * NE), dim3(256), 0, stream,
                       ent, counts, members, ent_emb);
    hipLaunchKernelGGL(k_attnmean, dim3(BB * NE, NH), dim3(256), 0, stream,
                       attn, counts, members, am);
    hipLaunchKernelGGL(k_hta, dim3(BB * RR), dim3(256), 0, stream,
                       am, hts, hta);
    hipLaunchKernelGGL(k_rel, dim3(RR / 64, HID / 64, BB), dim3(256), 0, stream,
                       hta, seq, rel);
    hipLaunchKernelGGL(k_headtail, dim3(NROWS / 64, EMB / 64), dim3(256), 0, stream,
                       ent_emb, rel, hts, W_head, b_head, hbuf, 0);
    hipLaunchKernelGGL(k_headtail, dim3(NROWS / 64, EMB / 64), dim3(256), 0, stream,
                       ent_emb, rel, hts, W_tail, b_tail, tbuf, 1);
    hipLaunchKernelGGL(k_bilinear, dim3(NROWS / 64, EMB / 64), dim3(256), 0, stream,
                       hbuf, tbuf, W_bil, b_bil, embeds_out);
    hipLaunchKernelGGL(k_cls, dim3(NROWS / 16), dim3(256), 0, stream,
                       embeds_out, W_cls, b_cls, W_proj, b_proj, cls_out, proj_out);
}

// Round 2
// 1181.193 us; speedup vs baseline: 3.3841x; 3.3841x over previous
//
#include <hip/hip_runtime.h>
#include <hip/hip_bf16.h>
#include <math.h>

// Problem constants (fixed shapes)
#define BB   4
#define LL   1024
#define MM   128
#define RR   512
#define HID  1024
#define NH   16
#define NE   42
#define EMB  768
#define NBK  12          // EMB/64
#define NC   97
#define PJ   128
#define NROWS 2048       // BB*RR
#define KTOT (NBK * 4096)   // 49152

typedef __attribute__((ext_vector_type(8))) short short8;
typedef __attribute__((ext_vector_type(4))) float floatx4;
typedef unsigned short ushort;

__device__ __forceinline__ float bf2f(ushort u) {
    return __uint_as_float(((unsigned int)u) << 16);
}
__device__ __forceinline__ ushort f2bf(float f) {
    __hip_bfloat16 h = __float2bfloat16(f);
    return *reinterpret_cast<ushort*>(&h);
}
__device__ __forceinline__ void async16(void* lds_base_uniform, const void* gsrc) {
    __builtin_amdgcn_global_load_lds(
        (const __attribute__((address_space(1))) unsigned int*)gsrc,
        (__attribute__((address_space(3))) unsigned int*)lds_base_uniform,
        16, 0, 0);
}

// ---------------------------------------------------------------------------
// K1: per-doc entity member lists + counts
// ---------------------------------------------------------------------------
__global__ __launch_bounds__(128) void k_members(const int* __restrict__ labels,
                                                 int* __restrict__ counts,
                                                 int* __restrict__ members) {
    int b = blockIdx.x;
    __shared__ int cnt[NE];
    int tid = threadIdx.x;
    if (tid < NE) cnt[tid] = 0;
    __syncthreads();
    if (tid < MM) {
        int lab = labels[b * MM + tid];
        int pos = atomicAdd(&cnt[lab], 1);
        members[(b * NE + lab) * MM + pos] = tid;
    }
    __syncthreads();
    if (tid < NE) counts[b * NE + tid] = cnt[tid];
}

// ---------------------------------------------------------------------------
// K2: ent_emb[b,e,d] = logsumexp over members of ent_lhs[b,m,d] (0 if empty)
// ---------------------------------------------------------------------------
__global__ __launch_bounds__(256) void k_entemb(const float* __restrict__ ent,
                                                const int* __restrict__ counts,
                                                const int* __restrict__ members,
                                                float* __restrict__ ent_emb) {
    int be = blockIdx.x;              // b*NE + e
    int b  = be / NE;
    int c  = counts[be];
    int tid = threadIdx.x;
    if (c == 0) {
#pragma unroll
        for (int u = 0; u < 4; ++u)
            ent_emb[(size_t)be * HID + tid + u * 256] = 0.0f;
        return;
    }
    const int* mem = members + be * MM;
    const float* base = ent + (size_t)b * MM * HID;
#pragma unroll
    for (int u = 0; u < 4; ++u) {
        int d = tid + u * 256;
        float mx = -3.0e38f;
        for (int k = 0; k < c; ++k) {
            float x = base[(size_t)mem[k] * HID + d];
            mx = fmaxf(mx, x);
        }
        float s = 0.0f;
        for (int k = 0; k < c; ++k) {
            float x = base[(size_t)mem[k] * HID + d];
            s += expf(x - mx);
        }
        ent_emb[(size_t)be * HID + d] = logf(s) + mx;
    }
}

// ---------------------------------------------------------------------------
// K3: attn_mean[b,e,h,l] = mean over members of attn[b,h,m,l]
// ---------------------------------------------------------------------------
__global__ __launch_bounds__(256) void k_attnmean(const float* __restrict__ attn,
                                                  const int* __restrict__ counts,
                                                  const int* __restrict__ members,
                                                  float* __restrict__ am) {
    int be = blockIdx.x;              // b*NE + e
    int hh = blockIdx.y;
    int b  = be / NE;
    int c  = counts[be];
    const int* mem = members + be * MM;
    float inv = 1.0f / (float)((c > 0) ? c : 1);
    const float* abase = attn + ((size_t)(b * NH + hh)) * MM * LL;
    int tid = threadIdx.x;
#pragma unroll
    for (int u = 0; u < 4; ++u) {
        int l = tid + u * 256;
        float s = 0.0f;
        for (int k = 0; k < c; ++k) s += abase[(size_t)mem[k] * LL + l];
        am[((size_t)be * NH + hh) * LL + l] = s * inv;
    }
}

// ---------------------------------------------------------------------------
// K4: hta[b,r,l] = normalized mean_h attn_mean[b,e0,h,l]*attn_mean[b,e1,h,l]
// ---------------------------------------------------------------------------
__global__ __launch_bounds__(256) void k_hta(const float* __restrict__ am,
                                             const int* __restrict__ hts,
                                             float* __restrict__ hta) {
    int br = blockIdx.x;              // b*RR + r
    int b  = br >> 9;
    int e0 = hts[br * 2 + 0];
    int e1 = hts[br * 2 + 1];
    const float* a0 = am + ((size_t)(b * NE + e0)) * NH * LL;
    const float* a1 = am + ((size_t)(b * NE + e1)) * NH * LL;
    int tid = threadIdx.x;
    float v[4] = {0.f, 0.f, 0.f, 0.f};
    for (int hh = 0; hh < NH; ++hh) {
        const float* p0 = a0 + hh * LL;
        const float* p1 = a1 + hh * LL;
#pragma unroll
        for (int u = 0; u < 4; ++u) {
            int l = tid + u * 256;
            v[u] = fmaf(p0[l], p1[l], v[u]);
        }
    }
    float part = 0.f;
#pragma unroll
    for (int u = 0; u < 4; ++u) { v[u] *= (1.0f / 16.0f); part += v[u]; }
    __shared__ float red[256];
    red[tid] = part;
    __syncthreads();
    for (int s = 128; s > 0; s >>= 1) {
        if (tid < s) red[tid] += red[tid + s];
        __syncthreads();
    }
    float scale = 1.0f / (red[0] + 1e-5f);
#pragma unroll
    for (int u = 0; u < 4; ++u)
        hta[(size_t)br * LL + tid + u * 256] = v[u] * scale;
}

// ---------------------------------------------------------------------------
// K5: rel[b] = hta[b] (512x1024) @ seq[b] (1024x1024)   tiled fp32 GEMM
// ---------------------------------------------------------------------------
__global__ __launch_bounds__(256) void k_rel(const float* __restrict__ hta,
                                             const float* __restrict__ seq,
                                             float* __restrict__ rel) {
    int b = blockIdx.z;
    const float* A  = hta + (size_t)b * RR * LL;
    const float* Bm = seq + (size_t)b * LL * HID;
    float* C = rel + (size_t)b * RR * HID;
    __shared__ float As[16][68];
    __shared__ float Bs[16][68];
    int tid = threadIdx.x;
    int tx = tid & 15, ty = tid >> 4;
    int row0 = blockIdx.x * 64, col0 = blockIdx.y * 64;
    float acc[4][4] = {};
    for (int k0 = 0; k0 < LL; k0 += 16) {
        {
            int kk4 = (tid & 3) << 2, m = tid >> 2;
            float4 va = *(const float4*)&A[(size_t)(row0 + m) * LL + k0 + kk4];
            As[kk4 + 0][m] = va.x; As[kk4 + 1][m] = va.y;
            As[kk4 + 2][m] = va.z; As[kk4 + 3][m] = va.w;
        }
        {
            int n4 = (tid & 15) << 2, kk = tid >> 4;
            float4 vb = *(const float4*)&Bm[(size_t)(k0 + kk) * HID + col0 + n4];
            *(float4*)&Bs[kk][n4] = vb;
        }
        __syncthreads();
#pragma unroll
        for (int kk = 0; kk < 16; ++kk) {
            float4 a4 = *(const float4*)&As[kk][ty << 2];
            float4 b4 = *(const float4*)&Bs[kk][tx << 2];
            float av[4] = {a4.x, a4.y, a4.z, a4.w};
            float bv[4] = {b4.x, b4.y, b4.z, b4.w};
#pragma unroll
            for (int q = 0; q < 4; ++q)
#pragma unroll
                for (int p = 0; p < 4; ++p)
                    acc[q][p] = fmaf(av[q], bv[p], acc[q][p]);
        }
        __syncthreads();
    }
#pragma unroll
    for (int q = 0; q < 4; ++q)
#pragma unroll
        for (int p = 0; p < 4; ++p)
            C[(size_t)(row0 + (ty << 2) + q) * HID + col0 + (tx << 2) + p] = acc[q][p];
}

// ---------------------------------------------------------------------------
// K6: h/t = tanh( [gather(ent_emb) | rel] (2048x2048) @ W (2048x768) + bias )
//     htcol==0 -> write bf16 TRANSPOSED hT[c][r]   (for bilinear LDS staging)
//     htcol==1 -> write bf16 row-major  tbf[r][c]  (for bilinear t-fragments)
// ---------------------------------------------------------------------------
__global__ __launch_bounds__(256) void k_headtail(const float* __restrict__ ent_emb,
                                                  const float* __restrict__ rel,
                                                  const int* __restrict__ hts,
                                                  const float* __restrict__ W,
                                                  const float* __restrict__ bias,
                                                  ushort* __restrict__ outT,
                                                  ushort* __restrict__ outR,
                                                  int htcol) {
    __shared__ float As[16][68];
    __shared__ float Bs[16][68];
    __shared__ int eofs[64];
    __shared__ int rofs[64];
    int tid = threadIdx.x;
    int tx = tid & 15, ty = tid >> 4;
    int row0 = blockIdx.x * 64, col0 = blockIdx.y * 64;
    if (tid < 64) {
        int r = row0 + tid;
        int b = r >> 9, rr = r & 511;
        int e = hts[(b * RR + rr) * 2 + htcol];
        eofs[tid] = (b * NE + e) * HID;
        rofs[tid] = (b * RR + rr) * HID;
    }
    __syncthreads();
    float acc[4][4] = {};
    for (int k0 = 0; k0 < 2 * HID; k0 += 16) {
        if (k0 < HID) {
#pragma unroll
            for (int u = 0; u < 4; ++u) {
                int idx = tid + u * 256;
                int m = idx >> 4, kk = idx & 15;
                As[kk][m] = ent_emb[(size_t)eofs[m] + k0 + kk];
            }
        } else {
#pragma unroll
            for (int u = 0; u < 4; ++u) {
                int idx = tid + u * 256;
                int m = idx >> 4, kk = idx & 15;
                As[kk][m] = rel[(size_t)rofs[m] + (k0 - HID) + kk];
            }
        }
        {
            int n4 = (tid & 15) << 2, kk = tid >> 4;
            float4 vb = *(const float4*)&W[(size_t)(k0 + kk) * EMB + col0 + n4];
            *(float4*)&Bs[kk][n4] = vb;
        }
        __syncthreads();
#pragma unroll
        for (int kk = 0; kk < 16; ++kk) {
            float4 a4 = *(const float4*)&As[kk][ty << 2];
            float4 b4 = *(const float4*)&Bs[kk][tx << 2];
            float av[4] = {a4.x, a4.y, a4.z, a4.w};
            float bv[4] = {b4.x, b4.y, b4.z, b4.w};
#pragma unroll
            for (int q = 0; q < 4; ++q)
#pragma unroll
                for (int p = 0; p < 4; ++p)
                    acc[q][p] = fmaf(av[q], bv[p], acc[q][p]);
        }
        __syncthreads();
    }
#pragma unroll
    for (int q = 0; q < 4; ++q)
#pragma unroll
        for (int p = 0; p < 4; ++p) {
            int cc = col0 + (tx << 2) + p;
            int rr = row0 + (ty << 2) + q;
            ushort v = f2bf(tanhf(acc[q][p] + bias[cc]));
            if (htcol == 0) outT[(size_t)cc * NROWS + rr] = v;
            else            outR[(size_t)rr * EMB + cc] = v;
        }
}

// ---------------------------------------------------------------------------
// K6b: pre-pack W_bil fp32 -> bf16 in MFMA-fragment streaming order.
// Tile (cb, nb, i) = 8KB: [f=ks*4+cg][lane][e] with
//   j = ks*32 + (lane>>4)*8 + e ; col = cb*64 + cg*16 + (lane&15)
//   W row = nb*4096 + i*64 + j.  Tiles ordered [cb][nb][i].
// ---------------------------------------------------------------------------
__global__ __launch_bounds__(256) void k_wprep(const float* __restrict__ W,
                                               ushort* __restrict__ wprep) {
    unsigned int flat = blockIdx.x * 256 + threadIdx.x;   // 16B-chunk id
    int l  = flat & 63;
    int f  = (flat >> 6) & 7;
    int i  = (flat >> 9) & 63;
    unsigned int rest = flat >> 15;          // 0..143
    int nb = rest % 12;
    int cb = rest / 12;
    int ks = f >> 2, cg = f & 3;
    int row = nb * 4096 + i * 64 + ks * 32 + ((l >> 4) & 3) * 8;
    int col = cb * 64 + cg * 16 + (l & 15);
    ushort out[8];
#pragma unroll
    for (int e = 0; e < 8; ++e)
        out[e] = f2bf(W[(size_t)(row + e) * EMB + col]);
    ushort* dst = wprep + (size_t)flat * 8;
#pragma unroll
    for (int e = 0; e < 8; ++e) dst[e] = out[e];
}

// ---------------------------------------------------------------------------
// K7: bilinear GEMM with MFMA, bl generated on the fly.
// Grid (rb 8, cb 12, nb 12); 256 thr = 4 waves; wave = 64 rows x 64 cols.
// ---------------------------------------------------------------------------
__global__ __launch_bounds__(256, 2) void k_bilinear(const ushort* __restrict__ hT,
                                                     const ushort* __restrict__ tbf,
                                                     const ushort* __restrict__ wprep,
                                                     float* __restrict__ partials) {
    __shared__ __align__(16) ushort h_lds[64 * 256];   // [i][r] 32KB
    __shared__ __align__(16) short  wlds[2 * 4096];    // 2 x 8KB W tiles

    const int tid  = threadIdx.x;
    const int lane = tid & 63;
    const int w    = tid >> 6;
    const int lan16 = lane & 15;
    const int lgrp  = lane >> 4;            // 0..3
    const int rb = blockIdx.x, cb = blockIdx.y, nb = blockIdx.z;
    const int row0 = rb * 256;
    const int col0 = cb * 64;
    const int rbase = w * 64;

    // stage hT[nb*64 + i][row0 .. row0+255] -> h_lds (linear dest, 8 passes)
#pragma unroll
    for (int c = 0; c < 8; ++c) {
        void* dst = (void*)&h_lds[c * 2048 + w * 512];   // +lane*16B by HW
        const ushort* src = hT + (size_t)(nb * 64 + c * 8 + w * 2 + (lane >> 5)) * NROWS
                               + row0 + (lane & 31) * 8;
        async16(dst, src);
    }
    // stage W tile i=0 into buf 0
    {
        const ushort* tsrc = wprep + ((size_t)((cb * 12 + nb) * 64 + 0)) * 4096;
        async16((void*)&wlds[w * 512],        tsrc + w * 512 + lane * 8);
        async16((void*)&wlds[2048 + w * 512], tsrc + 2048 + w * 512 + lane * 8);
    }

    // t-fragments for this wave (fixed across the i-loop)
    float tf[4][2][8];
#pragma unroll
    for (int rg = 0; rg < 4; ++rg) {
#pragma unroll
        for (int ks = 0; ks < 2; ++ks) {
            const ushort* tp = tbf + (size_t)(row0 + rbase + rg * 16 + lan16) * EMB
                                   + nb * 64 + ks * 32 + lgrp * 8;
            short8 raw = *(const short8*)tp;
#pragma unroll
            for (int e = 0; e < 8; ++e)
                tf[rg][ks][e] = bf2f((ushort)raw[e]);
        }
    }

    floatx4 acc[4][4];
#pragma unroll
    for (int rg = 0; rg < 4; ++rg)
#pragma unroll
        for (int cg = 0; cg < 4; ++cg)
            acc[rg][cg] = (floatx4){0.f, 0.f, 0.f, 0.f};

    __syncthreads();   // h_lds + W tile 0 ready (syncthreads drains vmcnt)

    int buf = 0;
    for (int i = 0; i < 64; ++i) {
        if (i < 63) {
            const ushort* tsrc = wprep + ((size_t)((cb * 12 + nb) * 64 + i + 1)) * 4096;
            int bn = buf ^ 1;
            async16((void*)&wlds[bn * 4096 + w * 512],        tsrc + w * 512 + lane * 8);
            async16((void*)&wlds[bn * 4096 + 2048 + w * 512], tsrc + 2048 + w * 512 + lane * 8);
        }
        float hv[4];
#pragma unroll
        for (int rg = 0; rg < 4; ++rg)
            hv[rg] = bf2f(h_lds[i * 256 + rbase + rg * 16 + lan16]);

#pragma unroll
        for (int ks = 0; ks < 2; ++ks) {
            short8 bfr[4];
#pragma unroll
            for (int cg = 0; cg < 4; ++cg)
                bfr[cg] = *(const short8*)&wlds[buf * 4096 + (ks * 4 + cg) * 512 + lane * 8];
#pragma unroll
            for (int rg = 0; rg < 4; ++rg) {
                short8 afr;
#pragma unroll
                for (int e = 0; e < 8; ++e)
                    afr[e] = (short)f2bf(hv[rg] * tf[rg][ks][e]);
#pragma unroll
                for (int cg = 0; cg < 4; ++cg)
                    acc[rg][cg] = __builtin_amdgcn_mfma_f32_16x16x32_bf16(
                        afr, bfr[cg], acc[rg][cg], 0, 0, 0);
            }
        }
        __syncthreads();
        buf ^= 1;
    }

    float* pbase = partials + (size_t)nb * NROWS * EMB;
#pragma unroll
    for (int rg = 0; rg < 4; ++rg)
#pragma unroll
        for (int cg = 0; cg < 4; ++cg)
#pragma unroll
            for (int q = 0; q < 4; ++q)
                pbase[(size_t)(row0 + rbase + rg * 16 + lgrp * 4 + q) * EMB
                      + col0 + cg * 16 + lan16] = acc[rg][cg][q];
}

// ---------------------------------------------------------------------------
// K7b: embeds = sum_nb partials[nb] + b_bil
// ---------------------------------------------------------------------------
__global__ __launch_bounds__(256) void k_redbias(const float* __restrict__ partials,
                                                 const float* __restrict__ bias,
                                                 float* __restrict__ embeds) {
    int idx = blockIdx.x * 256 + threadIdx.x;          // float4 index
    const float4* p4 = (const float4*)partials;
    float4 s = p4[idx];
#pragma unroll
    for (int nb = 1; nb < NBK; ++nb) {
        float4 v = p4[(size_t)nb * (NROWS * EMB / 4) + idx];
        s.x += v.x; s.y += v.y; s.z += v.z; s.w += v.w;
    }
    float4 b = ((const float4*)bias)[idx % (EMB / 4)];
    s.x += b.x; s.y += b.y; s.z += b.z; s.w += b.w;
    ((float4*)embeds)[idx] = s;
}

// ---------------------------------------------------------------------------
// K8: class_logits = embeds @ W_cls + b_cls ; proj = tanh(embeds @ W_proj + b)
// ---------------------------------------------------------------------------
__global__ __launch_bounds__(256) void k_cls(const float* __restrict__ embeds,
                                             const float* __restrict__ Wc,
                                             const float* __restrict__ bc,
                                             const float* __restrict__ Wp,
                                             const float* __restrict__ bp,
                                             float* __restrict__ cls_out,
                                             float* __restrict__ proj_out) {
    __shared__ float Es[16][769];
    int row0 = blockIdx.x * 16;
    int tid = threadIdx.x;
    for (int rr = 0; rr < 16; ++rr)
        for (int k = tid; k < EMB; k += 256)
            Es[rr][k] = embeds[(size_t)(row0 + rr) * EMB + k];
    __syncthreads();
    const int TOT = NC + PJ;   // 225
    for (int oi = tid; oi < 16 * TOT; oi += 256) {
        int r = oi / TOT;
        int c = oi - r * TOT;
        if (c < NC) {
            float acc = bc[c];
            for (int k = 0; k < EMB; ++k)
                acc = fmaf(Es[r][k], Wc[(size_t)k * NC + c], acc);
            cls_out[(size_t)(row0 + r) * NC + c] = acc;
        } else {
            int p = c - NC;
            float acc = bp[p];
            for (int k = 0; k < EMB; ++k)
                acc = fmaf(Es[r][k], Wp[(size_t)k * PJ + p], acc);
            proj_out[(size_t)(row0 + r) * PJ + p] = tanhf(acc);
        }
    }
}

// ---------------------------------------------------------------------------
extern "C" void kernel_launch(void* const* d_in, const int* in_sizes, int n_in,
                              void* d_out, int out_size, void* d_ws, size_t ws_size,
                              hipStream_t stream) {
    const float* seq    = (const float*)d_in[0];
    const float* ent    = (const float*)d_in[1];
    const float* attn   = (const float*)d_in[2];
    const int*   labels = (const int*)d_in[3];
    const int*   hts    = (const int*)d_in[4];
    const float* W_head = (const float*)d_in[5];
    const float* b_head = (const float*)d_in[6];
    const float* W_tail = (const float*)d_in[7];
    const float* b_tail = (const float*)d_in[8];
    const float* W_bil  = (const float*)d_in[9];
    const float* b_bil  = (const float*)d_in[10];
    const float* W_cls  = (const float*)d_in[11];
    const float* b_cls  = (const float*)d_in[12];
    const float* W_proj = (const float*)d_in[13];
    const float* b_proj = (const float*)d_in[14];

    // workspace layout (256B-aligned regions) -- ~186 MB total
    char* p = (char*)d_ws;
    auto alloc = [&](size_t bytes) {
        void* r = (void*)p;
        p += (bytes + 255) & ~(size_t)255;
        return r;
    };
    int*    counts   = (int*)alloc(256 * 4);
    int*    members  = (int*)alloc((size_t)BB * NE * MM * 4);
    float*  ent_emb  = (float*)alloc((size_t)BB * NE * HID * 4);
    float*  am       = (float*)alloc((size_t)BB * NE * NH * LL * 4);
    float*  hta      = (float*)alloc((size_t)BB * RR * LL * 4);
    float*  rel      = (float*)alloc((size_t)BB * RR * HID * 4);
    ushort* hT       = (ushort*)alloc((size_t)EMB * NROWS * 2);
    ushort* tbf      = (ushort*)alloc((size_t)NROWS * EMB * 2);
    ushort* wprep    = (ushort*)alloc((size_t)KTOT * EMB * 2);
    float*  partials = (float*)alloc((size_t)NBK * NROWS * EMB * 4);

    float* embeds_out = (float*)d_out;                    // 2048*768
    float* cls_out    = embeds_out + NROWS * EMB;         // 2048*97
    float* proj_out   = cls_out + NROWS * NC;             // 2048*128

    hipLaunchKernelGGL(k_wprep, dim3((KTOT * EMB / 8) / 256), dim3(256), 0, stream,
                       W_bil, wprep);
    hipLaunchKernelGGL(k_members, dim3(BB), dim3(128), 0, stream,
                       labels, counts, members);
    hipLaunchKernelGGL(k_entemb, dim3(BB * NE), dim3(256), 0, stream,
                       ent, counts, members, ent_emb);
    hipLaunchKernelGGL(k_attnmean, dim3(BB * NE, NH), dim3(256), 0, stream,
                       attn, counts, members, am);
    hipLaunchKernelGGL(k_hta, dim3(BB * RR), dim3(256), 0, stream,
                       am, hts, hta);
    hipLaunchKernelGGL(k_rel, dim3(RR / 64, HID / 64, BB), dim3(256), 0, stream,
                       hta, seq, rel);
    hipLaunchKernelGGL(k_headtail, dim3(NROWS / 64, EMB / 64), dim3(256), 0, stream,
                       ent_emb, rel, hts, W_head, b_head, hT, tbf, 0);
    hipLaunchKernelGGL(k_headtail, dim3(NROWS / 64, EMB / 64), dim3(256), 0, stream,
                       ent_emb, rel, hts, W_tail, b_tail, hT, tbf, 1);
    hipLaunchKernelGGL(k_bilinear, dim3(NROWS / 256, EMB / 64, NBK), dim3(256), 0, stream,
                       hT, tbf, wprep, partials);
    hipLaunchKernelGGL(k_redbias, dim3(NROWS * EMB / 4 / 256), dim3(256), 0, stream,
                       partials, b_bil, embeds_out);
    hipLaunchKernelGGL(k_cls, dim3(NROWS / 16), dim3(256), 0, stream,
                       embeds_out, W_cls, b_cls, W_proj, b_proj, cls_out, proj_out);
}

// Round 3
// 702.328 us; speedup vs baseline: 5.6915x; 1.6818x over previous
//
#include <hip/hip_runtime.h>
#include <hip/hip_bf16.h>
#include <math.h>

// Problem constants (fixed shapes)
#define BB   4
#define LL   1024
#define MM   128
#define RR   512
#define HID  1024
#define NH   16
#define NE   42
#define EMB  768
#define NBK  12          // EMB/64
#define NC   97
#define PJ   128
#define NROWS 2048       // BB*RR
#define KTOT (NBK * 4096)   // 49152

typedef __attribute__((ext_vector_type(8))) short short8;
typedef __attribute__((ext_vector_type(4))) float floatx4;
typedef unsigned short ushort;

__device__ __forceinline__ float bf2f(ushort u) {
    return __uint_as_float(((unsigned int)u) << 16);
}
__device__ __forceinline__ ushort f2bf(float f) {
    __hip_bfloat16 h = __float2bfloat16(f);
    return *reinterpret_cast<ushort*>(&h);
}
__device__ __forceinline__ void async16(void* lds_base_uniform, const void* gsrc) {
    __builtin_amdgcn_global_load_lds(
        (const __attribute__((address_space(1))) unsigned int*)gsrc,
        (__attribute__((address_space(3))) unsigned int*)lds_base_uniform,
        16, 0, 0);
}
// stage one 8KB W tile-pair (tile t, t in units of 4096 ushorts) into wlds[bn]
__device__ __forceinline__ void stage_w(short (*wlds)[4096], int bn,
                                        const ushort* wsrc, size_t t,
                                        int w, int lane) {
    const ushort* ts = wsrc + t * 4096;
    async16((void*)&wlds[bn][w * 512],        ts + w * 512 + lane * 8);
    async16((void*)&wlds[bn][2048 + w * 512], ts + 2048 + w * 512 + lane * 8);
}

// ---------------------------------------------------------------------------
// K1: per-doc entity member lists + counts
// ---------------------------------------------------------------------------
__global__ __launch_bounds__(128) void k_members(const int* __restrict__ labels,
                                                 int* __restrict__ counts,
                                                 int* __restrict__ members) {
    int b = blockIdx.x;
    __shared__ int cnt[NE];
    int tid = threadIdx.x;
    if (tid < NE) cnt[tid] = 0;
    __syncthreads();
    if (tid < MM) {
        int lab = labels[b * MM + tid];
        int pos = atomicAdd(&cnt[lab], 1);
        members[(b * NE + lab) * MM + pos] = tid;
    }
    __syncthreads();
    if (tid < NE) counts[b * NE + tid] = cnt[tid];
}

// ---------------------------------------------------------------------------
// K2: ent_emb_bf[b,e,d] = bf16( logsumexp over members ) (0 if empty)
// ---------------------------------------------------------------------------
__global__ __launch_bounds__(256) void k_entemb(const float* __restrict__ ent,
                                                const int* __restrict__ counts,
                                                const int* __restrict__ members,
                                                ushort* __restrict__ entbf) {
    int be = blockIdx.x;              // b*NE + e
    int b  = be / NE;
    int c  = counts[be];
    int tid = threadIdx.x;
    if (c == 0) {
#pragma unroll
        for (int u = 0; u < 4; ++u)
            entbf[(size_t)be * HID + tid + u * 256] = 0;
        return;
    }
    const int* mem = members + be * MM;
    const float* base = ent + (size_t)b * MM * HID;
#pragma unroll
    for (int u = 0; u < 4; ++u) {
        int d = tid + u * 256;
        float mx = -3.0e38f;
        for (int k = 0; k < c; ++k) {
            float x = base[(size_t)mem[k] * HID + d];
            mx = fmaxf(mx, x);
        }
        float s = 0.0f;
        for (int k = 0; k < c; ++k) {
            float x = base[(size_t)mem[k] * HID + d];
            s += expf(x - mx);
        }
        entbf[(size_t)be * HID + d] = f2bf(logf(s) + mx);
    }
}

// ---------------------------------------------------------------------------
// K3: attn_mean[b,e,h,l] = mean over members of attn[b,h,m,l]
// ---------------------------------------------------------------------------
__global__ __launch_bounds__(256) void k_attnmean(const float* __restrict__ attn,
                                                  const int* __restrict__ counts,
                                                  const int* __restrict__ members,
                                                  float* __restrict__ am) {
    int be = blockIdx.x;              // b*NE + e
    int hh = blockIdx.y;
    int b  = be / NE;
    int c  = counts[be];
    const int* mem = members + be * MM;
    float inv = 1.0f / (float)((c > 0) ? c : 1);
    const float* abase = attn + ((size_t)(b * NH + hh)) * MM * LL;
    int tid = threadIdx.x;
#pragma unroll
    for (int u = 0; u < 4; ++u) {
        int l = tid + u * 256;
        float s = 0.0f;
        for (int k = 0; k < c; ++k) s += abase[(size_t)mem[k] * LL + l];
        am[((size_t)be * NH + hh) * LL + l] = s * inv;
    }
}

// ---------------------------------------------------------------------------
// K4: hta_bf[b,r,l] = bf16(normalized mean_h am[b,e0,h,l]*am[b,e1,h,l])
// ---------------------------------------------------------------------------
__global__ __launch_bounds__(256) void k_hta(const float* __restrict__ am,
                                             const int* __restrict__ hts,
                                             ushort* __restrict__ htabf) {
    int br = blockIdx.x;              // b*RR + r
    int b  = br >> 9;
    int e0 = hts[br * 2 + 0];
    int e1 = hts[br * 2 + 1];
    const float* a0 = am + ((size_t)(b * NE + e0)) * NH * LL;
    const float* a1 = am + ((size_t)(b * NE + e1)) * NH * LL;
    int tid = threadIdx.x;
    float v[4] = {0.f, 0.f, 0.f, 0.f};
    for (int hh = 0; hh < NH; ++hh) {
        const float* p0 = a0 + hh * LL;
        const float* p1 = a1 + hh * LL;
#pragma unroll
        for (int u = 0; u < 4; ++u) {
            int l = tid + u * 256;
            v[u] = fmaf(p0[l], p1[l], v[u]);
        }
    }
    float part = 0.f;
#pragma unroll
    for (int u = 0; u < 4; ++u) { v[u] *= (1.0f / 16.0f); part += v[u]; }
    __shared__ float red[256];
    red[tid] = part;
    __syncthreads();
    for (int s = 128; s > 0; s >>= 1) {
        if (tid < s) red[tid] += red[tid + s];
        __syncthreads();
    }
    float scale = 1.0f / (red[0] + 1e-5f);
#pragma unroll
    for (int u = 0; u < 4; ++u)
        htabf[(size_t)br * LL + tid + u * 256] = f2bf(v[u] * scale);
}

// ---------------------------------------------------------------------------
// K_prepB: generic fp32 [K][N] (optionally batched) -> bf16 MFMA B-fragment
// streaming order: flat chunk F = (((bt*NCB + cb)*NK0 + k0)*4 + cg)*64 + lane,
// chunk = 8 bf16 along k: k = k0*32 + (lane>>4)*8 + e, col = cb*64+cg*16+(lane&15)
// ---------------------------------------------------------------------------
__global__ __launch_bounds__(256) void k_prepB(const float* __restrict__ src,
                                               ushort* __restrict__ dst,
                                               int K, int N, long srcStride) {
    long flat = (long)blockIdx.x * 256 + threadIdx.x;
    int lane = (int)(flat & 63);
    long rest = flat >> 6;
    int cg = (int)(rest & 3); rest >>= 2;
    int NK0 = K >> 5;
    int k0 = (int)(rest % NK0); rest /= NK0;
    int NCB = N >> 6;
    int cb = (int)(rest % NCB);
    int bt = (int)(rest / NCB);
    int col = cb * 64 + cg * 16 + (lane & 15);
    int k   = k0 * 32 + (lane >> 4) * 8;
    const float* s = src + (size_t)bt * srcStride + (size_t)k * N + col;
    short8 out;
#pragma unroll
    for (int e = 0; e < 8; ++e)
        out[e] = (short)f2bf(s[(size_t)e * N]);
    *(short8*)(dst + (size_t)flat * 8) = out;
}

// ---------------------------------------------------------------------------
// K5: rel_bf = hta_bf (512x1024) @ seq_prep (1024x1024)  bf16 MFMA, per doc
// Grid (4, 16, 4 docs); 256 thr = 4 waves; wave = 32 rows x 64 cols.
// ---------------------------------------------------------------------------
__global__ __launch_bounds__(256) void k_rel_mfma(const ushort* __restrict__ htabf,
                                                  const ushort* __restrict__ seqprep,
                                                  ushort* __restrict__ relbf) {
    __shared__ __align__(16) short wlds[2][4096];
    const int b = blockIdx.z;
    const int tid = threadIdx.x, lane = tid & 63, w = tid >> 6;
    const int lan16 = lane & 15, lgrp = lane >> 4;
    const int row0 = blockIdx.x * 128, cb = blockIdx.y, col0 = cb * 64;
    const ushort* wsrc = seqprep + ((size_t)b * 16 + cb) * 32 * 2048;
    const ushort* aP[2];
#pragma unroll
    for (int rg = 0; rg < 2; ++rg) {
        int r = row0 + w * 32 + rg * 16 + lan16;
        aP[rg] = htabf + ((size_t)b * RR + r) * LL;
    }
    floatx4 acc[2][4];
#pragma unroll
    for (int rg = 0; rg < 2; ++rg)
#pragma unroll
        for (int cg = 0; cg < 4; ++cg)
            acc[rg][cg] = (floatx4){0.f, 0.f, 0.f, 0.f};

    stage_w(wlds, 0, wsrc, 0, w, lane);
    __syncthreads();
    int buf = 0;
    for (int it = 0; it < 16; ++it) {
        short8 afr[2][2];
#pragma unroll
        for (int rg = 0; rg < 2; ++rg)
#pragma unroll
            for (int ks = 0; ks < 2; ++ks)
                afr[rg][ks] = *(const short8*)(aP[rg] + it * 64 + ks * 32 + lgrp * 8);
        if (it < 15) stage_w(wlds, buf ^ 1, wsrc, it + 1, w, lane);
#pragma unroll
        for (int ks = 0; ks < 2; ++ks) {
            short8 bfr[4];
#pragma unroll
            for (int cg = 0; cg < 4; ++cg)
                bfr[cg] = *(const short8*)&wlds[buf][ks * 2048 + cg * 512 + lane * 8];
#pragma unroll
            for (int rg = 0; rg < 2; ++rg)
#pragma unroll
                for (int cg = 0; cg < 4; ++cg)
                    acc[rg][cg] = __builtin_amdgcn_mfma_f32_16x16x32_bf16(
                        afr[rg][ks], bfr[cg], acc[rg][cg], 0, 0, 0);
        }
        __syncthreads();
        buf ^= 1;
    }
#pragma unroll
    for (int rg = 0; rg < 2; ++rg)
#pragma unroll
        for (int cg = 0; cg < 4; ++cg)
#pragma unroll
            for (int q = 0; q < 4; ++q) {
                int rr = row0 + w * 32 + rg * 16 + lgrp * 4 + q;
                int cc = col0 + cg * 16 + lan16;
                relbf[((size_t)b * RR + rr) * HID + cc] = f2bf(acc[rg][cg][q]);
            }
}

// ---------------------------------------------------------------------------
// K6: h/t = tanh( [gather(ent_bf) | rel_bf] (2048x2048) @ W (2048x768) + b )
// bf16 MFMA. Grid (16, 12, z=2): z=0 head -> hT[c][r], z=1 tail -> tbf[r][c].
// ---------------------------------------------------------------------------
__global__ __launch_bounds__(256) void k_ht_mfma(const ushort* __restrict__ entbf,
                                                 const ushort* __restrict__ relbf,
                                                 const int* __restrict__ hts,
                                                 const ushort* __restrict__ wprepH,
                                                 const ushort* __restrict__ wprepT,
                                                 const float* __restrict__ bH,
                                                 const float* __restrict__ bT,
                                                 ushort* __restrict__ hT,
                                                 ushort* __restrict__ tbf) {
    __shared__ __align__(16) short wlds[2][4096];
    const int z = blockIdx.z;
    const ushort* wp  = z ? wprepT : wprepH;
    const float* bias = z ? bT : bH;
    const int tid = threadIdx.x, lane = tid & 63, w = tid >> 6;
    const int lan16 = lane & 15, lgrp = lane >> 4;
    const int row0 = blockIdx.x * 128, cb = blockIdx.y, col0 = cb * 64;
    const ushort* wsrc = wp + (size_t)cb * 64 * 2048;   // 64 K-tiles per col-tile
    const ushort* aE[2];
    const ushort* aR[2];
#pragma unroll
    for (int rg = 0; rg < 2; ++rg) {
        int r = row0 + w * 32 + rg * 16 + lan16;
        int b = r >> 9, rr = r & 511;
        int e = hts[(b * RR + rr) * 2 + z];
        aE[rg] = entbf + (size_t)(b * NE + e) * HID;
        aR[rg] = relbf + (size_t)r * HID;
    }
    floatx4 acc[2][4];
#pragma unroll
    for (int rg = 0; rg < 2; ++rg)
#pragma unroll
        for (int cg = 0; cg < 4; ++cg)
            acc[rg][cg] = (floatx4){0.f, 0.f, 0.f, 0.f};

    stage_w(wlds, 0, wsrc, 0, w, lane);
    __syncthreads();
    int buf = 0;
    for (int it = 0; it < 32; ++it) {
        short8 afr[2][2];
        const int kb = (it < 16) ? it * 64 : it * 64 - 1024;
#pragma unroll
        for (int rg = 0; rg < 2; ++rg) {
            const ushort* ap = (it < 16 ? aE[rg] : aR[rg]) + kb + lgrp * 8;
#pragma unroll
            for (int ks = 0; ks < 2; ++ks)
                afr[rg][ks] = *(const short8*)(ap + ks * 32);
        }
        if (it < 31) stage_w(wlds, buf ^ 1, wsrc, it + 1, w, lane);
#pragma unroll
        for (int ks = 0; ks < 2; ++ks) {
            short8 bfr[4];
#pragma unroll
            for (int cg = 0; cg < 4; ++cg)
                bfr[cg] = *(const short8*)&wlds[buf][ks * 2048 + cg * 512 + lane * 8];
#pragma unroll
            for (int rg = 0; rg < 2; ++rg)
#pragma unroll
                for (int cg = 0; cg < 4; ++cg)
                    acc[rg][cg] = __builtin_amdgcn_mfma_f32_16x16x32_bf16(
                        afr[rg][ks], bfr[cg], acc[rg][cg], 0, 0, 0);
        }
        __syncthreads();
        buf ^= 1;
    }
#pragma unroll
    for (int rg = 0; rg < 2; ++rg)
#pragma unroll
        for (int cg = 0; cg < 4; ++cg)
#pragma unroll
            for (int q = 0; q < 4; ++q) {
                int rr = row0 + w * 32 + rg * 16 + lgrp * 4 + q;
                int cc = col0 + cg * 16 + lan16;
                ushort v = f2bf(tanhf(acc[rg][cg][q] + bias[cc]));
                if (z == 0) hT[(size_t)cc * NROWS + rr] = v;
                else        tbf[(size_t)rr * EMB + cc] = v;
            }
}

// ---------------------------------------------------------------------------
// K7: bilinear GEMM with MFMA, bl generated on the fly. Split-K = 4:
// grid (rb 8, cb 12, zz 4); each block covers nb in [zz*3, zz*3+3).
// ---------------------------------------------------------------------------
__global__ __launch_bounds__(256, 2) void k_bilinear(const ushort* __restrict__ hT,
                                                     const ushort* __restrict__ tbf,
                                                     const ushort* __restrict__ wprep,
                                                     float* __restrict__ partials) {
    __shared__ __align__(16) ushort h_lds[64 * 256];   // [i][r] 32KB
    __shared__ __align__(16) short  wlds[2][4096];     // 2 x 8KB W tiles

    const int tid  = threadIdx.x;
    const int lane = tid & 63;
    const int w    = tid >> 6;
    const int lan16 = lane & 15;
    const int lgrp  = lane >> 4;
    const int rb = blockIdx.x, cb = blockIdx.y, zz = blockIdx.z;
    const int nb0 = zz * 3;
    const int row0 = rb * 256;
    const int col0 = cb * 64;
    const int rbase = w * 64;
    // W tile stream for nb in [nb0, nb0+3): contiguous 192 tiles
    const ushort* wsrc = wprep + (size_t)((cb * 12 + nb0) * 64) * 4096;

    floatx4 acc[4][4];
#pragma unroll
    for (int rg = 0; rg < 4; ++rg)
#pragma unroll
        for (int cg = 0; cg < 4; ++cg)
            acc[rg][cg] = (floatx4){0.f, 0.f, 0.f, 0.f};

    stage_w(wlds, 0, wsrc, 0, w, lane);
    int buf = 0;
    for (int nbi = 0; nbi < 3; ++nbi) {
        const int nb = nb0 + nbi;
        // stage hT[nb*64 + i][row0..row0+255] -> h_lds (linear dest)
#pragma unroll
        for (int c = 0; c < 8; ++c) {
            void* dst = (void*)&h_lds[c * 2048 + w * 512];
            const ushort* src = hT + (size_t)(nb * 64 + c * 8 + w * 2 + (lane >> 5)) * NROWS
                                   + row0 + (lane & 31) * 8;
            async16(dst, src);
        }
        // t-fragments for this nb
        float tf[4][2][8];
#pragma unroll
        for (int rg = 0; rg < 4; ++rg)
#pragma unroll
            for (int ks = 0; ks < 2; ++ks) {
                const ushort* tp = tbf + (size_t)(row0 + rbase + rg * 16 + lan16) * EMB
                                       + nb * 64 + ks * 32 + lgrp * 8;
                short8 raw = *(const short8*)tp;
#pragma unroll
                for (int e = 0; e < 8; ++e)
                    tf[rg][ks][e] = bf2f((ushort)raw[e]);
            }
        __syncthreads();   // h_lds + pending W tile ready

        for (int i = 0; i < 64; ++i) {
            const int t = nbi * 64 + i;
            if (t < 191) stage_w(wlds, buf ^ 1, wsrc, t + 1, w, lane);
            float hv[4];
#pragma unroll
            for (int rg = 0; rg < 4; ++rg)
                hv[rg] = bf2f(h_lds[i * 256 + rbase + rg * 16 + lan16]);
#pragma unroll
            for (int ks = 0; ks < 2; ++ks) {
                short8 bfr[4];
#pragma unroll
                for (int cg = 0; cg < 4; ++cg)
                    bfr[cg] = *(const short8*)&wlds[buf][ks * 2048 + cg * 512 + lane * 8];
#pragma unroll
                for (int rg = 0; rg < 4; ++rg) {
                    short8 afr;
#pragma unroll
                    for (int e = 0; e < 8; ++e)
                        afr[e] = (short)f2bf(hv[rg] * tf[rg][ks][e]);
#pragma unroll
                    for (int cg = 0; cg < 4; ++cg)
                        acc[rg][cg] = __builtin_amdgcn_mfma_f32_16x16x32_bf16(
                            afr, bfr[cg], acc[rg][cg], 0, 0, 0);
                }
            }
            __syncthreads();
            buf ^= 1;
        }
    }

    float* pbase = partials + (size_t)zz * NROWS * EMB;
#pragma unroll
    for (int rg = 0; rg < 4; ++rg)
#pragma unroll
        for (int cg = 0; cg < 4; ++cg)
#pragma unroll
            for (int q = 0; q < 4; ++q)
                pbase[(size_t)(row0 + rbase + rg * 16 + lgrp * 4 + q) * EMB
                      + col0 + cg * 16 + lan16] = acc[rg][cg][q];
}

// ---------------------------------------------------------------------------
// K7b: embeds = sum_{zz<4} partials[zz] + b_bil
// ---------------------------------------------------------------------------
__global__ __launch_bounds__(256) void k_redbias(const float* __restrict__ partials,
                                                 const float* __restrict__ bias,
                                                 float* __restrict__ embeds) {
    int idx = blockIdx.x * 256 + threadIdx.x;          // float4 index
    const float4* p4 = (const float4*)partials;
    float4 s = p4[idx];
#pragma unroll
    for (int zz = 1; zz < 4; ++zz) {
        float4 v = p4[(size_t)zz * (NROWS * EMB / 4) + idx];
        s.x += v.x; s.y += v.y; s.z += v.z; s.w += v.w;
    }
    float4 b = ((const float4*)bias)[idx % (EMB / 4)];
    s.x += b.x; s.y += b.y; s.z += b.z; s.w += b.w;
    ((float4*)embeds)[idx] = s;
}

// ---------------------------------------------------------------------------
// K8a: Wcomb[k][c] = c<97 ? W_cls[k][c] : (c<225 ? W_proj[k][c-97] : 0)
// ---------------------------------------------------------------------------
__global__ __launch_bounds__(256) void k_wcomb(const float* __restrict__ Wc,
                                               const float* __restrict__ Wp,
                                               float* __restrict__ Wcomb) {
    int k = blockIdx.x;
    int c = threadIdx.x;
    float v = (c < NC) ? Wc[(size_t)k * NC + c]
                       : ((c < NC + PJ) ? Wp[(size_t)k * PJ + (c - NC)] : 0.0f);
    Wcomb[(size_t)k * 256 + c] = v;
}

// ---------------------------------------------------------------------------
// K8: tiled fp32 GEMM: [cls|proj] = embeds(2048x768) @ Wcomb(768x256)
// ---------------------------------------------------------------------------
__global__ __launch_bounds__(256) void k_cls(const float* __restrict__ embeds,
                                             const float* __restrict__ Wcomb,
                                             const float* __restrict__ bc,
                                             const float* __restrict__ bp,
                                             float* __restrict__ cls_out,
                                             float* __restrict__ proj_out) {
    __shared__ float As[16][68];
    __shared__ float Bs[16][68];
    int tid = threadIdx.x;
    int tx = tid & 15, ty = tid >> 4;
    int row0 = blockIdx.x * 64, col0 = blockIdx.y * 64;
    float acc[4][4] = {};
    for (int k0 = 0; k0 < EMB; k0 += 16) {
        {
            int kk4 = (tid & 3) << 2, m = tid >> 2;
            float4 va = *(const float4*)&embeds[(size_t)(row0 + m) * EMB + k0 + kk4];
            As[kk4 + 0][m] = va.x; As[kk4 + 1][m] = va.y;
            As[kk4 + 2][m] = va.z; As[kk4 + 3][m] = va.w;
        }
        {
            int n4 = (tid & 15) << 2, kk = tid >> 4;
            float4 vb = *(const float4*)&Wcomb[(size_t)(k0 + kk) * 256 + col0 + n4];
            *(float4*)&Bs[kk][n4] = vb;
        }
        __syncthreads();
#pragma unroll
        for (int kk = 0; kk < 16; ++kk) {
            float4 a4 = *(const float4*)&As[kk][ty << 2];
            float4 b4 = *(const float4*)&Bs[kk][tx << 2];
            float av[4] = {a4.x, a4.y, a4.z, a4.w};
            float bv[4] = {b4.x, b4.y, b4.z, b4.w};
#pragma unroll
            for (int q = 0; q < 4; ++q)
#pragma unroll
                for (int p = 0; p < 4; ++p)
                    acc[q][p] = fmaf(av[q], bv[p], acc[q][p]);
        }
        __syncthreads();
    }
#pragma unroll
    for (int q = 0; q < 4; ++q)
#pragma unroll
        for (int p = 0; p < 4; ++p) {
            int c = col0 + (tx << 2) + p;
            int r = row0 + (ty << 2) + q;
            if (c < NC) {
                cls_out[(size_t)r * NC + c] = acc[q][p] + bc[c];
            } else if (c < NC + PJ) {
                int pp = c - NC;
                proj_out[(size_t)r * PJ + pp] = tanhf(acc[q][p] + bp[pp]);
            }
        }
}

// ---------------------------------------------------------------------------
extern "C" void kernel_launch(void* const* d_in, const int* in_sizes, int n_in,
                              void* d_out, int out_size, void* d_ws, size_t ws_size,
                              hipStream_t stream) {
    const float* seq    = (const float*)d_in[0];
    const float* ent    = (const float*)d_in[1];
    const float* attn   = (const float*)d_in[2];
    const int*   labels = (const int*)d_in[3];
    const int*   hts    = (const int*)d_in[4];
    const float* W_head = (const float*)d_in[5];
    const float* b_head = (const float*)d_in[6];
    const float* W_tail = (const float*)d_in[7];
    const float* b_tail = (const float*)d_in[8];
    const float* W_bil  = (const float*)d_in[9];
    const float* b_bil  = (const float*)d_in[10];
    const float* W_cls  = (const float*)d_in[11];
    const float* b_cls  = (const float*)d_in[12];
    const float* W_proj = (const float*)d_in[13];
    const float* b_proj = (const float*)d_in[14];

    // workspace layout (256B-aligned regions) -- ~141 MB total
    char* p = (char*)d_ws;
    auto alloc = [&](size_t bytes) {
        void* r = (void*)p;
        p += (bytes + 255) & ~(size_t)255;
        return r;
    };
    int*    counts   = (int*)alloc(256 * 4);
    int*    members  = (int*)alloc((size_t)BB * NE * MM * 4);
    ushort* entbf    = (ushort*)alloc((size_t)BB * NE * HID * 2);
    float*  am       = (float*)alloc((size_t)BB * NE * NH * LL * 4);
    ushort* htabf    = (ushort*)alloc((size_t)BB * RR * LL * 2);
    ushort* relbf    = (ushort*)alloc((size_t)NROWS * HID * 2);
    ushort* hT       = (ushort*)alloc((size_t)EMB * NROWS * 2);
    ushort* tbf      = (ushort*)alloc((size_t)NROWS * EMB * 2);
    ushort* wprepBil = (ushort*)alloc((size_t)KTOT * EMB * 2);
    ushort* wprepH   = (ushort*)alloc((size_t)2 * HID * EMB * 2);
    ushort* wprepT   = (ushort*)alloc((size_t)2 * HID * EMB * 2);
    ushort* seqprep  = (ushort*)alloc((size_t)BB * LL * HID * 2);
    float*  Wcomb    = (float*)alloc((size_t)EMB * 256 * 4);
    float*  partials = (float*)alloc((size_t)4 * NROWS * EMB * 4);

    float* embeds_out = (float*)d_out;                    // 2048*768
    float* cls_out    = embeds_out + NROWS * EMB;         // 2048*97
    float* proj_out   = cls_out + NROWS * NC;             // 2048*128

    // weight pre-packs (independent of activations)
    hipLaunchKernelGGL(k_prepB, dim3((size_t)KTOT * EMB / 8 / 256), dim3(256), 0, stream,
                       W_bil, wprepBil, KTOT, EMB, 0L);
    hipLaunchKernelGGL(k_prepB, dim3(2 * HID * EMB / 8 / 256), dim3(256), 0, stream,
                       W_head, wprepH, 2 * HID, EMB, 0L);
    hipLaunchKernelGGL(k_prepB, dim3(2 * HID * EMB / 8 / 256), dim3(256), 0, stream,
                       W_tail, wprepT, 2 * HID, EMB, 0L);
    hipLaunchKernelGGL(k_prepB, dim3(BB * LL * HID / 8 / 256), dim3(256), 0, stream,
                       seq, seqprep, LL, HID, (long)LL * HID);
    hipLaunchKernelGGL(k_wcomb, dim3(EMB), dim3(256), 0, stream,
                       W_cls, W_proj, Wcomb);

    // pooling
    hipLaunchKernelGGL(k_members, dim3(BB), dim3(128), 0, stream,
                       labels, counts, members);
    hipLaunchKernelGGL(k_entemb, dim3(BB * NE), dim3(256), 0, stream,
                       ent, counts, members, entbf);
    hipLaunchKernelGGL(k_attnmean, dim3(BB * NE, NH), dim3(256), 0, stream,
                       attn, counts, members, am);
    hipLaunchKernelGGL(k_hta, dim3(BB * RR), dim3(256), 0, stream,
                       am, hts, htabf);

    // GEMM chain
    hipLaunchKernelGGL(k_rel_mfma, dim3(RR / 128, HID / 64, BB), dim3(256), 0, stream,
                       htabf, seqprep, relbf);
    hipLaunchKernelGGL(k_ht_mfma, dim3(NROWS / 128, EMB / 64, 2), dim3(256), 0, stream,
                       entbf, relbf, hts, wprepH, wprepT, b_head, b_tail, hT, tbf);
    hipLaunchKernelGGL(k_bilinear, dim3(NROWS / 256, EMB / 64, 4), dim3(256), 0, stream,
                       hT, tbf, wprepBil, partials);
    hipLaunchKernelGGL(k_redbias, dim3(NROWS * EMB / 4 / 256), dim3(256), 0, stream,
                       partials, b_bil, embeds_out);
    hipLaunchKernelGGL(k_cls, dim3(NROWS / 64, 4), dim3(256), 0, stream,
                       embeds_out, Wcomb, b_cls, b_proj, cls_out, proj_out);
}

// Round 5
// 635.064 us; speedup vs baseline: 6.2944x; 1.1059x over previous
//
#include <hip/hip_runtime.h>
#include <hip/hip_bf16.h>
#include <math.h>

// Problem constants (fixed shapes)
#define BB   4
#define LL   1024
#define MM   128
#define RR   512
#define HID  1024
#define NH   16
#define NE   42
#define EMB  768
#define NBK  12          // EMB/64
#define NC   97
#define PJ   128
#define NROWS 2048       // BB*RR
#define KTOT (NBK * 4096)   // 49152

typedef __attribute__((ext_vector_type(8))) short short8;
typedef __attribute__((ext_vector_type(4))) float floatx4;
typedef unsigned short ushort;

__device__ __forceinline__ float bf2f(ushort u) {
    return __uint_as_float(((unsigned int)u) << 16);
}
__device__ __forceinline__ ushort f2bf(float f) {
    __hip_bfloat16 h = __float2bfloat16(f);
    return *reinterpret_cast<ushort*>(&h);
}
__device__ __forceinline__ void async16(void* lds_base_uniform, const void* gsrc) {
    __builtin_amdgcn_global_load_lds(
        (const __attribute__((address_space(1))) unsigned int*)gsrc,
        (__attribute__((address_space(3))) unsigned int*)lds_base_uniform,
        16, 0, 0);
}
// stage one 8KB W tile-pair (tile t, t in units of 4096 ushorts) into wlds[bn]
__device__ __forceinline__ void stage_w(short (*wlds)[4096], int bn,
                                        const ushort* wsrc, size_t t,
                                        int w, int lane) {
    const ushort* ts = wsrc + t * 4096;
    async16((void*)&wlds[bn][w * 512],        ts + w * 512 + lane * 8);
    async16((void*)&wlds[bn][2048 + w * 512], ts + 2048 + w * 512 + lane * 8);
}

// ---------------------------------------------------------------------------
// K1: per-doc entity member lists + counts
// ---------------------------------------------------------------------------
__global__ __launch_bounds__(128) void k_members(const int* __restrict__ labels,
                                                 int* __restrict__ counts,
                                                 int* __restrict__ members) {
    int b = blockIdx.x;
    __shared__ int cnt[NE];
    int tid = threadIdx.x;
    if (tid < NE) cnt[tid] = 0;
    __syncthreads();
    if (tid < MM) {
        int lab = labels[b * MM + tid];
        int pos = atomicAdd(&cnt[lab], 1);
        members[(b * NE + lab) * MM + pos] = tid;
    }
    __syncthreads();
    if (tid < NE) counts[b * NE + tid] = cnt[tid];
}

// ---------------------------------------------------------------------------
// K2: ent_emb_bf[b,e,d] = bf16( logsumexp over members ) (0 if empty)
// ---------------------------------------------------------------------------
__global__ __launch_bounds__(256) void k_entemb(const float* __restrict__ ent,
                                                const int* __restrict__ counts,
                                                const int* __restrict__ members,
                                                ushort* __restrict__ entbf) {
    int be = blockIdx.x;              // b*NE + e
    int b  = be / NE;
    int c  = counts[be];
    int tid = threadIdx.x;
    if (c == 0) {
#pragma unroll
        for (int u = 0; u < 4; ++u)
            entbf[(size_t)be * HID + tid + u * 256] = 0;
        return;
    }
    const int* mem = members + be * MM;
    const float* base = ent + (size_t)b * MM * HID;
#pragma unroll
    for (int u = 0; u < 4; ++u) {
        int d = tid + u * 256;
        float mx = -3.0e38f;
        for (int k = 0; k < c; ++k) {
            float x = base[(size_t)mem[k] * HID + d];
            mx = fmaxf(mx, x);
        }
        float s = 0.0f;
        for (int k = 0; k < c; ++k) {
            float x = base[(size_t)mem[k] * HID + d];
            s += expf(x - mx);
        }
        entbf[(size_t)be * HID + d] = f2bf(logf(s) + mx);
    }
}

// ---------------------------------------------------------------------------
// K3: attn_mean[b,e,h,l] = mean over members of attn[b,h,m,l]
// ---------------------------------------------------------------------------
__global__ __launch_bounds__(256) void k_attnmean(const float* __restrict__ attn,
                                                  const int* __restrict__ counts,
                                                  const int* __restrict__ members,
                                                  float* __restrict__ am) {
    int be = blockIdx.x;              // b*NE + e
    int hh = blockIdx.y;
    int b  = be / NE;
    int c  = counts[be];
    const int* mem = members + be * MM;
    float inv = 1.0f / (float)((c > 0) ? c : 1);
    const float* abase = attn + ((size_t)(b * NH + hh)) * MM * LL;
    int tid = threadIdx.x;
#pragma unroll
    for (int u = 0; u < 4; ++u) {
        int l = tid + u * 256;
        float s = 0.0f;
        for (int k = 0; k < c; ++k) s += abase[(size_t)mem[k] * LL + l];
        am[((size_t)be * NH + hh) * LL + l] = s * inv;
    }
}

// ---------------------------------------------------------------------------
// K4: hta_bf[b,r,l] = bf16(normalized mean_h am[b,e0,h,l]*am[b,e1,h,l])
// ---------------------------------------------------------------------------
__global__ __launch_bounds__(256) void k_hta(const float* __restrict__ am,
                                             const int* __restrict__ hts,
                                             ushort* __restrict__ htabf) {
    int br = blockIdx.x;              // b*RR + r
    int b  = br >> 9;
    int e0 = hts[br * 2 + 0];
    int e1 = hts[br * 2 + 1];
    const float* a0 = am + ((size_t)(b * NE + e0)) * NH * LL;
    const float* a1 = am + ((size_t)(b * NE + e1)) * NH * LL;
    int tid = threadIdx.x;
    float v[4] = {0.f, 0.f, 0.f, 0.f};
    for (int hh = 0; hh < NH; ++hh) {
        const float* p0 = a0 + hh * LL;
        const float* p1 = a1 + hh * LL;
#pragma unroll
        for (int u = 0; u < 4; ++u) {
            int l = tid + u * 256;
            v[u] = fmaf(p0[l], p1[l], v[u]);
        }
    }
    float part = 0.f;
#pragma unroll
    for (int u = 0; u < 4; ++u) { v[u] *= (1.0f / 16.0f); part += v[u]; }
    __shared__ float red[256];
    red[tid] = part;
    __syncthreads();
    for (int s = 128; s > 0; s >>= 1) {
        if (tid < s) red[tid] += red[tid + s];
        __syncthreads();
    }
    float scale = 1.0f / (red[0] + 1e-5f);
#pragma unroll
    for (int u = 0; u < 4; ++u)
        htabf[(size_t)br * LL + tid + u * 256] = f2bf(v[u] * scale);
}

// ---------------------------------------------------------------------------
// K_prepB: generic fp32 [K][N] (optionally batched) -> bf16 MFMA B-fragment
// streaming order: flat chunk F = (((bt*NCB + cb)*NK0 + k0)*4 + cg)*64 + lane,
// chunk = 8 bf16 along k: k = k0*32 + (lane>>4)*8 + e, col = cb*64+cg*16+(lane&15)
// ---------------------------------------------------------------------------
__global__ __launch_bounds__(256) void k_prepB(const float* __restrict__ src,
                                               ushort* __restrict__ dst,
                                               int K, int N, long srcStride) {
    long flat = (long)blockIdx.x * 256 + threadIdx.x;
    int lane = (int)(flat & 63);
    long rest = flat >> 6;
    int cg = (int)(rest & 3); rest >>= 2;
    int NK0 = K >> 5;
    int k0 = (int)(rest % NK0); rest /= NK0;
    int NCB = N >> 6;
    int cb = (int)(rest % NCB);
    int bt = (int)(rest / NCB);
    int col = cb * 64 + cg * 16 + (lane & 15);
    int k   = k0 * 32 + (lane >> 4) * 8;
    const float* s = src + (size_t)bt * srcStride + (size_t)k * N + col;
    short8 out;
#pragma unroll
    for (int e = 0; e < 8; ++e)
        out[e] = (short)f2bf(s[(size_t)e * N]);
    *(short8*)(dst + (size_t)flat * 8) = out;
}

// ---------------------------------------------------------------------------
// K5: rel_bf = hta_bf (512x1024) @ seq_prep (1024x1024)  bf16 MFMA, per doc
// Grid (4, 16, 4 docs); 256 thr = 4 waves; wave = 32 rows x 64 cols.
// ---------------------------------------------------------------------------
__global__ __launch_bounds__(256) void k_rel_mfma(const ushort* __restrict__ htabf,
                                                  const ushort* __restrict__ seqprep,
                                                  ushort* __restrict__ relbf) {
    __shared__ __align__(16) short wlds[2][4096];
    const int b = blockIdx.z;
    const int tid = threadIdx.x, lane = tid & 63, w = tid >> 6;
    const int lan16 = lane & 15, lgrp = lane >> 4;
    const int row0 = blockIdx.x * 128, cb = blockIdx.y, col0 = cb * 64;
    const ushort* wsrc = seqprep + ((size_t)b * 16 + cb) * 32 * 2048;
    const ushort* aP[2];
#pragma unroll
    for (int rg = 0; rg < 2; ++rg) {
        int r = row0 + w * 32 + rg * 16 + lan16;
        aP[rg] = htabf + ((size_t)b * RR + r) * LL;
    }
    floatx4 acc[2][4];
#pragma unroll
    for (int rg = 0; rg < 2; ++rg)
#pragma unroll
        for (int cg = 0; cg < 4; ++cg)
            acc[rg][cg] = (floatx4){0.f, 0.f, 0.f, 0.f};

    stage_w(wlds, 0, wsrc, 0, w, lane);
    __syncthreads();
    int buf = 0;
    for (int it = 0; it < 16; ++it) {
        short8 afr[2][2];
#pragma unroll
        for (int rg = 0; rg < 2; ++rg)
#pragma unroll
            for (int ks = 0; ks < 2; ++ks)
                afr[rg][ks] = *(const short8*)(aP[rg] + it * 64 + ks * 32 + lgrp * 8);
        if (it < 15) stage_w(wlds, buf ^ 1, wsrc, it + 1, w, lane);
#pragma unroll
        for (int ks = 0; ks < 2; ++ks) {
            short8 bfr[4];
#pragma unroll
            for (int cg = 0; cg < 4; ++cg)
                bfr[cg] = *(const short8*)&wlds[buf][ks * 2048 + cg * 512 + lane * 8];
#pragma unroll
            for (int rg = 0; rg < 2; ++rg)
#pragma unroll
                for (int cg = 0; cg < 4; ++cg)
                    acc[rg][cg] = __builtin_amdgcn_mfma_f32_16x16x32_bf16(
                        afr[rg][ks], bfr[cg], acc[rg][cg], 0, 0, 0);
        }
        __syncthreads();
        buf ^= 1;
    }
#pragma unroll
    for (int rg = 0; rg < 2; ++rg)
#pragma unroll
        for (int cg = 0; cg < 4; ++cg)
#pragma unroll
            for (int q = 0; q < 4; ++q) {
                int rr = row0 + w * 32 + rg * 16 + lgrp * 4 + q;
                int cc = col0 + cg * 16 + lan16;
                relbf[((size_t)b * RR + rr) * HID + cc] = f2bf(acc[rg][cg][q]);
            }
}

// ---------------------------------------------------------------------------
// K6: h/t = tanh( [gather(ent_bf) | rel_bf] (2048x2048) @ W (2048x768) + b )
// bf16 MFMA. Grid (16, 12, z=2): z=0 head -> hT[c][r], z=1 tail -> tbf[r][c].
// ---------------------------------------------------------------------------
__global__ __launch_bounds__(256) void k_ht_mfma(const ushort* __restrict__ entbf,
                                                 const ushort* __restrict__ relbf,
                                                 const int* __restrict__ hts,
                                                 const ushort* __restrict__ wprepH,
                                                 const ushort* __restrict__ wprepT,
                                                 const float* __restrict__ bH,
                                                 const float* __restrict__ bT,
                                                 ushort* __restrict__ hT,
                                                 ushort* __restrict__ tbf) {
    __shared__ __align__(16) short wlds[2][4096];
    const int z = blockIdx.z;
    const ushort* wp  = z ? wprepT : wprepH;
    const float* bias = z ? bT : bH;
    const int tid = threadIdx.x, lane = tid & 63, w = tid >> 6;
    const int lan16 = lane & 15, lgrp = lane >> 4;
    const int row0 = blockIdx.x * 128, cb = blockIdx.y, col0 = cb * 64;
    const ushort* wsrc = wp + (size_t)cb * 64 * 2048;   // 64 K-tiles per col-tile
    const ushort* aE[2];
    const ushort* aR[2];
#pragma unroll
    for (int rg = 0; rg < 2; ++rg) {
        int r = row0 + w * 32 + rg * 16 + lan16;
        int b = r >> 9, rr = r & 511;
        int e = hts[(b * RR + rr) * 2 + z];
        aE[rg] = entbf + (size_t)(b * NE + e) * HID;
        aR[rg] = relbf + (size_t)r * HID;
    }
    floatx4 acc[2][4];
#pragma unroll
    for (int rg = 0; rg < 2; ++rg)
#pragma unroll
        for (int cg = 0; cg < 4; ++cg)
            acc[rg][cg] = (floatx4){0.f, 0.f, 0.f, 0.f};

    stage_w(wlds, 0, wsrc, 0, w, lane);
    __syncthreads();
    int buf = 0;
    for (int it = 0; it < 32; ++it) {
        short8 afr[2][2];
        const int kb = (it < 16) ? it * 64 : it * 64 - 1024;
#pragma unroll
        for (int rg = 0; rg < 2; ++rg) {
            const ushort* ap = (it < 16 ? aE[rg] : aR[rg]) + kb + lgrp * 8;
#pragma unroll
            for (int ks = 0; ks < 2; ++ks)
                afr[rg][ks] = *(const short8*)(ap + ks * 32);
        }
        if (it < 31) stage_w(wlds, buf ^ 1, wsrc, it + 1, w, lane);
#pragma unroll
        for (int ks = 0; ks < 2; ++ks) {
            short8 bfr[4];
#pragma unroll
            for (int cg = 0; cg < 4; ++cg)
                bfr[cg] = *(const short8*)&wlds[buf][ks * 2048 + cg * 512 + lane * 8];
#pragma unroll
            for (int rg = 0; rg < 2; ++rg)
#pragma unroll
                for (int cg = 0; cg < 4; ++cg)
                    acc[rg][cg] = __builtin_amdgcn_mfma_f32_16x16x32_bf16(
                        afr[rg][ks], bfr[cg], acc[rg][cg], 0, 0, 0);
        }
        __syncthreads();
        buf ^= 1;
    }
#pragma unroll
    for (int rg = 0; rg < 2; ++rg)
#pragma unroll
        for (int cg = 0; cg < 4; ++cg)
#pragma unroll
            for (int q = 0; q < 4; ++q) {
                int rr = row0 + w * 32 + rg * 16 + lgrp * 4 + q;
                int cc = col0 + cg * 16 + lan16;
                ushort v = f2bf(tanhf(acc[rg][cg][q] + bias[cc]));
                if (z == 0) hT[(size_t)cc * NROWS + rr] = v;
                else        tbf[(size_t)rr * EMB + cc] = v;
            }
}

// ---------------------------------------------------------------------------
// K7: bilinear GEMM with MFMA, bl generated on the fly.
// Grid: 768 blocks 1D, XCD-swizzled so the 16 row-blocks sharing one W stream
// colocate on one XCD (L2-hot). Block: 4 waves x (32 rows x 64 cols) = 128x64.
// Each block covers nb in [zz*3, zz*3+3); 2 i-steps per barrier.
// LDS: h 16KB + 2x16KB W double-buffer = 48KB -> 3 blocks/CU.
// ---------------------------------------------------------------------------
__global__ __launch_bounds__(256, 3) void k_bilinear(const ushort* __restrict__ hT,
                                                     const ushort* __restrict__ tbf,
                                                     const ushort* __restrict__ wprep,
                                                     float* __restrict__ partials) {
    __shared__ __align__(16) ushort h_lds[64 * 128];   // [i][r] 16KB
    __shared__ __align__(16) short  wlds[2][8192];     // 2 x 16KB (2 W tiles each)

    const int tid  = threadIdx.x;
    const int lane = tid & 63;
    const int w    = tid >> 6;
    const int lan16 = lane & 15;
    const int lgrp  = lane >> 4;
    // swizzled decode: group g = (cb,zz) pinned to XCD g%8; rb = member
    const int L   = blockIdx.x;
    const int xcd = L & 7;
    const int t_  = L >> 3;
    const int rb  = t_ & 15;
    const int gq  = t_ >> 4;            // 0..5
    const int g   = gq * 8 + xcd;       // 0..47
    const int cb  = g >> 2;
    const int zz  = g & 3;
    const int nb0 = zz * 3;
    const int row0 = rb * 128;
    const int col0 = cb * 64;
    const int rbase = w * 32;
    // W tile stream for nb in [nb0, nb0+3): contiguous 192 tiles = 96 pairs
    const ushort* wsrc = wprep + (size_t)((cb * 12 + nb0) * 64) * 4096;

    // stage a 16KB W pair (tiles 2p, 2p+1) into wlds[bn]
    auto stage_w2 = [&](int bn, int p) {
        const ushort* ts = wsrc + (size_t)p * 8192;
#pragma unroll
        for (int s = 0; s < 4; ++s) {
            int m = s * 4 + w;
            async16((void*)&wlds[bn][m * 512], ts + m * 512 + lane * 8);
        }
    };
    // stage hT[nb*64 .. +64][row0 .. row0+128] -> h_lds[i][r] (16KB)
    auto stage_h = [&](int nb) {
#pragma unroll
        for (int s = 0; s < 4; ++s) {
            int m = s * 4 + w;
            async16((void*)&h_lds[m * 512],
                    hT + (size_t)(nb * 64 + m * 4 + (lane >> 4)) * NROWS
                       + row0 + lan16 * 8);
        }
    };

    floatx4 acc[2][4];
#pragma unroll
    for (int rg = 0; rg < 2; ++rg)
#pragma unroll
        for (int cg = 0; cg < 4; ++cg)
            acc[rg][cg] = (floatx4){0.f, 0.f, 0.f, 0.f};

    stage_w2(0, 0);
    int buf = 0;
    for (int nbi = 0; nbi < 3; ++nbi) {
        const int nb = nb0 + nbi;
        stage_h(nb);
        // t-fragments for this nb (registers, fixed over i)
        float tf[2][2][8];
#pragma unroll
        for (int rg = 0; rg < 2; ++rg)
#pragma unroll
            for (int ks = 0; ks < 2; ++ks) {
                const ushort* tp = tbf + (size_t)(row0 + rbase + rg * 16 + lan16) * EMB
                                       + nb * 64 + ks * 32 + lgrp * 8;
                short8 raw = *(const short8*)tp;
#pragma unroll
                for (int e = 0; e < 8; ++e)
                    tf[rg][ks][e] = bf2f((ushort)raw[e]);
            }
        __syncthreads();   // h_lds + pending W pair ready (drains vmcnt)

        for (int p = 0; p < 32; ++p) {
            const int pp = nbi * 32 + p;
            if (pp < 95) stage_w2(buf ^ 1, pp + 1);
#pragma unroll
            for (int ii = 0; ii < 2; ++ii) {
                const int i = p * 2 + ii;
                float hv[2];
#pragma unroll
                for (int rg = 0; rg < 2; ++rg)
                    hv[rg] = bf2f(h_lds[i * 128 + rbase + rg * 16 + lan16]);
#pragma unroll
                for (int ks = 0; ks < 2; ++ks) {
                    short8 bfr[4];
#pragma unroll
                    for (int cg = 0; cg < 4; ++cg)
                        bfr[cg] = *(const short8*)&wlds[buf][ii * 4096 + ks * 2048
                                                            + cg * 512 + lane * 8];
#pragma unroll
                    for (int rg = 0; rg < 2; ++rg) {
                        short8 afr;
#pragma unroll
                        for (int e = 0; e < 8; ++e)
                            afr[e] = (short)f2bf(hv[rg] * tf[rg][ks][e]);
#pragma unroll
                        for (int cg = 0; cg < 4; ++cg)
                            acc[rg][cg] = __builtin_amdgcn_mfma_f32_16x16x32_bf16(
                                afr, bfr[cg], acc[rg][cg], 0, 0, 0);
                    }
                }
            }
            __syncthreads();
            buf ^= 1;
        }
    }

    float* pbase = partials + (size_t)zz * NROWS * EMB;
#pragma unroll
    for (int rg = 0; rg < 2; ++rg)
#pragma unroll
        for (int cg = 0; cg < 4; ++cg)
#pragma unroll
            for (int q = 0; q < 4; ++q)
                pbase[(size_t)(row0 + rbase + rg * 16 + lgrp * 4 + q) * EMB
                      + col0 + cg * 16 + lan16] = acc[rg][cg][q];
}

// ---------------------------------------------------------------------------
// K7b: embeds = sum_{zz<4} partials[zz] + b_bil
// ---------------------------------------------------------------------------
__global__ __launch_bounds__(256) void k_redbias(const float* __restrict__ partials,
                                                 const float* __restrict__ bias,
                                                 float* __restrict__ embeds) {
    int idx = blockIdx.x * 256 + threadIdx.x;          // float4 index
    const float4* p4 = (const float4*)partials;
    float4 s = p4[idx];
#pragma unroll
    for (int zz = 1; zz < 4; ++zz) {
        float4 v = p4[(size_t)zz * (NROWS * EMB / 4) + idx];
        s.x += v.x; s.y += v.y; s.z += v.z; s.w += v.w;
    }
    float4 b = ((const float4*)bias)[idx % (EMB / 4)];
    s.x += b.x; s.y += b.y; s.z += b.z; s.w += b.w;
    ((float4*)embeds)[idx] = s;
}

// ---------------------------------------------------------------------------
// K8a: Wcomb[k][c] = c<97 ? W_cls[k][c] : (c<225 ? W_proj[k][c-97] : 0)
// ---------------------------------------------------------------------------
__global__ __launch_bounds__(256) void k_wcomb(const float* __restrict__ Wc,
                                               const float* __restrict__ Wp,
                                               float* __restrict__ Wcomb) {
    int k = blockIdx.x;
    int c = threadIdx.x;
    float v = (c < NC) ? Wc[(size_t)k * NC + c]
                       : ((c < NC + PJ) ? Wp[(size_t)k * PJ + (c - NC)] : 0.0f);
    Wcomb[(size_t)k * 256 + c] = v;
}

// ---------------------------------------------------------------------------
// K8: tiled fp32 GEMM: [cls|proj] = embeds(2048x768) @ Wcomb(768x256)
// ---------------------------------------------------------------------------
__global__ __launch_bounds__(256) void k_cls(const float* __restrict__ embeds,
                                             const float* __restrict__ Wcomb,
                                             const float* __restrict__ bc,
                                             const float* __restrict__ bp,
                                             float* __restrict__ cls_out,
                                             float* __restrict__ proj_out) {
    __shared__ float As[16][68];
    __shared__ float Bs[16][68];
    int tid = threadIdx.x;
    int tx = tid & 15, ty = tid >> 4;
    int row0 = blockIdx.x * 64, col0 = blockIdx.y * 64;
    float acc[4][4] = {};
    for (int k0 = 0; k0 < EMB; k0 += 16) {
        {
            int kk4 = (tid & 3) << 2, m = tid >> 2;
            float4 va = *(const float4*)&embeds[(size_t)(row0 + m) * EMB + k0 + kk4];
            As[kk4 + 0][m] = va.x; As[kk4 + 1][m] = va.y;
            As[kk4 + 2][m] = va.z; As[kk4 + 3][m] = va.w;
        }
        {
            int n4 = (tid & 15) << 2, kk = tid >> 4;
            float4 vb = *(const float4*)&Wcomb[(size_t)(k0 + kk) * 256 + col0 + n4];
            *(float4*)&Bs[kk][n4] = vb;
        }
        __syncthreads();
#pragma unroll
        for (int kk = 0; kk < 16; ++kk) {
            float4 a4 = *(const float4*)&As[kk][ty << 2];
            float4 b4 = *(const float4*)&Bs[kk][tx << 2];
            float av[4] = {a4.x, a4.y, a4.z, a4.w};
            float bv[4] = {b4.x, b4.y, b4.z, b4.w};
#pragma unroll
            for (int q = 0; q < 4; ++q)
#pragma unroll
                for (int p = 0; p < 4; ++p)
                    acc[q][p] = fmaf(av[q], bv[p], acc[q][p]);
        }
        __syncthreads();
    }
#pragma unroll
    for (int q = 0; q < 4; ++q)
#pragma unroll
        for (int p = 0; p < 4; ++p) {
            int c = col0 + (tx << 2) + p;
            int r = row0 + (ty << 2) + q;
            if (c < NC) {
                cls_out[(size_t)r * NC + c] = acc[q][p] + bc[c];
            } else if (c < NC + PJ) {
                int pp = c - NC;
                proj_out[(size_t)r * PJ + pp] = tanhf(acc[q][p] + bp[pp]);
            }
        }
}

// ---------------------------------------------------------------------------
extern "C" void kernel_launch(void* const* d_in, const int* in_sizes, int n_in,
                              void* d_out, int out_size, void* d_ws, size_t ws_size,
                              hipStream_t stream) {
    const float* seq    = (const float*)d_in[0];
    const float* ent    = (const float*)d_in[1];
    const float* attn   = (const float*)d_in[2];
    const int*   labels = (const int*)d_in[3];
    const int*   hts    = (const int*)d_in[4];
    const float* W_head = (const float*)d_in[5];
    const float* b_head = (const float*)d_in[6];
    const float* W_tail = (const float*)d_in[7];
    const float* b_tail = (const float*)d_in[8];
    const float* W_bil  = (const float*)d_in[9];
    const float* b_bil  = (const float*)d_in[10];
    const float* W_cls  = (const float*)d_in[11];
    const float* b_cls  = (const float*)d_in[12];
    const float* W_proj = (const float*)d_in[13];
    const float* b_proj = (const float*)d_in[14];

    // workspace layout (256B-aligned regions) -- ~141 MB total
    char* p = (char*)d_ws;
    auto alloc = [&](size_t bytes) {
        void* r = (void*)p;
        p += (bytes + 255) & ~(size_t)255;
        return r;
    };
    int*    counts   = (int*)alloc(256 * 4);
    int*    members  = (int*)alloc((size_t)BB * NE * MM * 4);
    ushort* entbf    = (ushort*)alloc((size_t)BB * NE * HID * 2);
    float*  am       = (float*)alloc((size_t)BB * NE * NH * LL * 4);
    ushort* htabf    = (ushort*)alloc((size_t)BB * RR * LL * 2);
    ushort* relbf    = (ushort*)alloc((size_t)NROWS * HID * 2);
    ushort* hT       = (ushort*)alloc((size_t)EMB * NROWS * 2);
    ushort* tbf      = (ushort*)alloc((size_t)NROWS * EMB * 2);
    ushort* wprepBil = (ushort*)alloc((size_t)KTOT * EMB * 2);
    ushort* wprepH   = (ushort*)alloc((size_t)2 * HID * EMB * 2);
    ushort* wprepT   = (ushort*)alloc((size_t)2 * HID * EMB * 2);
    ushort* seqprep  = (ushort*)alloc((size_t)BB * LL * HID * 2);
    float*  Wcomb    = (float*)alloc((size_t)EMB * 256 * 4);
    float*  partials = (float*)alloc((size_t)4 * NROWS * EMB * 4);

    float* embeds_out = (float*)d_out;                    // 2048*768
    float* cls_out    = embeds_out + NROWS * EMB;         // 2048*97
    float* proj_out   = cls_out + NROWS * NC;             // 2048*128

    // weight pre-packs (independent of activations)
    hipLaunchKernelGGL(k_prepB, dim3((size_t)KTOT * EMB / 8 / 256), dim3(256), 0, stream,
                       W_bil, wprepBil, KTOT, EMB, 0L);
    hipLaunchKernelGGL(k_prepB, dim3(2 * HID * EMB / 8 / 256), dim3(256), 0, stream,
                       W_head, wprepH, 2 * HID, EMB, 0L);
    hipLaunchKernelGGL(k_prepB, dim3(2 * HID * EMB / 8 / 256), dim3(256), 0, stream,
                       W_tail, wprepT, 2 * HID, EMB, 0L);
    hipLaunchKernelGGL(k_prepB, dim3(BB * LL * HID / 8 / 256), dim3(256), 0, stream,
                       seq, seqprep, LL, HID, (long)LL * HID);
    hipLaunchKernelGGL(k_wcomb, dim3(EMB), dim3(256), 0, stream,
                       W_cls, W_proj, Wcomb);

    // pooling
    hipLaunchKernelGGL(k_members, dim3(BB), dim3(128), 0, stream,
                       labels, counts, members);
    hipLaunchKernelGGL(k_entemb, dim3(BB * NE), dim3(256), 0, stream,
                       ent, counts, members, entbf);
    hipLaunchKernelGGL(k_attnmean, dim3(BB * NE, NH), dim3(256), 0, stream,
                       attn, counts, members, am);
    hipLaunchKernelGGL(k_hta, dim3(BB * RR), dim3(256), 0, stream,
                       am, hts, htabf);

    // GEMM chain
    hipLaunchKernelGGL(k_rel_mfma, dim3(RR / 128, HID / 64, BB), dim3(256), 0, stream,
                       htabf, seqprep, relbf);
    hipLaunchKernelGGL(k_ht_mfma, dim3(NROWS / 128, EMB / 64, 2), dim3(256), 0, stream,
                       entbf, relbf, hts, wprepH, wprepT, b_head, b_tail, hT, tbf);
    hipLaunchKernelGGL(k_bilinear, dim3(768), dim3(256), 0, stream,
                       hT, tbf, wprepBil, partials);
    hipLaunchKernelGGL(k_redbias, dim3(NROWS * EMB / 4 / 256), dim3(256), 0, stream,
                       partials, b_bil, embeds_out);
    hipLaunchKernelGGL(k_cls, dim3(NROWS / 64, 4), dim3(256), 0, stream,
                       embeds_out, Wcomb, b_cls, b_proj, cls_out, proj_out);
}